// Round 7
// baseline (446.056 us; speedup 1.0000x reference)
//
#include <hip/hip_runtime.h>
#include <hip/hip_bf16.h>

typedef unsigned short u16;
typedef __attribute__((ext_vector_type(8))) short short8;   // 8 bf16 = 4 VGPRs
typedef __attribute__((ext_vector_type(4))) short short4v;  // 4 bf16 = 8 B
typedef __attribute__((ext_vector_type(4))) float floatx4;  // MFMA C/D

#define D_MODEL 1024
#define NH 16
#define SEQ 2048
#define BATCH 4
#define M_ROWS 8192
#define N_QKV 3072

// Q-path prescale: 1/sqrt(64) * log2(e) so softmax is exp2(s - 8*log2e)
#define QSCALE 0.18033688011112042f
#define EXP2_OFF 11.541560327111707f   // 8 * log2(e)

__device__ __forceinline__ u16 f2u(float f) {
    __hip_bfloat16 h = __float2bfloat16(f);
    u16 u; __builtin_memcpy(&u, &h, 2); return u;
}

// async global->LDS, 16B per lane; dest = wave-uniform base + lane*16
__device__ __forceinline__ void async_copy16(const u16* g, u16* l) {
    __builtin_amdgcn_global_load_lds(
        (const __attribute__((address_space(1))) unsigned int*)(g),
        (__attribute__((address_space(3))) unsigned int*)(l),
        16, 0, 0);
}

// ---------------------------------------------------------------------------
// prep (one launch): blocks 0..4095 convert x->bf16; 4096..5119 transpose
// weights (Wq pre-scaled by QSCALE); block 5120 packs biases.
// ---------------------------------------------------------------------------
__global__ __launch_bounds__(256) void prep(
    const float* __restrict__ x,
    const float* __restrict__ Wq, const float* __restrict__ Wk,
    const float* __restrict__ Wv, const float* __restrict__ Wo,
    const float* __restrict__ bq, const float* __restrict__ bk,
    const float* __restrict__ bv, const float* __restrict__ bo,
    u16* __restrict__ xb, u16* __restrict__ Wpt, u16* __restrict__ Wot,
    float* __restrict__ biasp)
{
    __shared__ u16 T[64 * 72];
    const int tid = threadIdx.x;
    const int blk = blockIdx.x;

    if (blk < 4096) {                       // x -> bf16
        size_t i = ((size_t)blk * 256 + tid) * 8;
        float4 f0 = *(const float4*)&x[i];
        float4 f1 = *(const float4*)&x[i + 4];
        u16 t[8] = {f2u(f0.x), f2u(f0.y), f2u(f0.z), f2u(f0.w),
                    f2u(f1.x), f2u(f1.y), f2u(f1.z), f2u(f1.w)};
        *(short8*)&xb[i] = *(short8*)t;
        return;
    }
    if (blk == 5120) {                      // biases
        #pragma unroll
        for (int j = 0; j < 16; j++) {
            int idx = j * 256 + tid;
            float v;
            if (idx < 1024)      v = bq[idx] * QSCALE;
            else if (idx < 2048) v = bk[idx - 1024];
            else if (idx < 3072) v = bv[idx - 2048];
            else                 v = bo[idx - 3072];
            biasp[idx] = v;
        }
        return;
    }
    const int wb = blk - 4096;              // 0..1023: weight transpose
    const int r = tid >> 2, s4 = (tid & 3) * 16;
    if (wb < 768) {
        int sel = wb / 256, rem = wb % 256;
        int h = rem >> 4, ktile = rem & 15;
        const float* W = (sel == 0) ? Wq : ((sel == 1) ? Wk : Wv);
        const float scale = (sel == 0) ? QSCALE : 1.0f;
        const float* src = W + ((size_t)h * 1024 + ktile * 64 + r) * 64 + s4;
        #pragma unroll
        for (int i = 0; i < 16; i++) T[(s4 + i) * 72 + r] = f2u(src[i] * scale);
        __syncthreads();
        u16 tmp[16];
        #pragma unroll
        for (int i = 0; i < 16; i++) tmp[i] = T[r * 72 + s4 + i];
        u16* dst = Wpt + ((size_t)sel * 1024 + h * 64 + r) * 1024 + ktile * 64 + s4;
        *(short8*)&dst[0] = *(short8*)&tmp[0];
        *(short8*)&dst[8] = *(short8*)&tmp[8];
    } else {
        int rem = wb - 768;
        int nt = rem >> 4, kt2 = rem & 15;
        const float* src = Wo + ((size_t)kt2 * 64 + r) * 1024 + nt * 64 + s4;
        #pragma unroll
        for (int i = 0; i < 16; i++) T[(s4 + i) * 72 + r] = f2u(src[i]);
        __syncthreads();
        u16 tmp[16];
        #pragma unroll
        for (int i = 0; i < 16; i++) tmp[i] = T[r * 72 + s4 + i];
        u16* dst = Wot + ((size_t)nt * 64 + r) * 1024 + kt2 * 64 + s4;
        *(short8*)&dst[0] = *(short8*)&tmp[0];
        *(short8*)&dst[8] = *(short8*)&tmp[8];
    }
}

// ---------------------------------------------------------------------------
// vtrans: V slice of QKV -> Vtg[bh][d][key] via LDS tile.
// ---------------------------------------------------------------------------
__global__ __launch_bounds__(256) void vtrans(const u16* __restrict__ QKV,
                                              u16* __restrict__ Vtg) {
    __shared__ u16 T[64 * 72];
    const int bh = blockIdx.x, kt = blockIdx.y;
    const int b = bh >> 4, h = bh & 15;
    const int tid = threadIdx.x;
    const int r = tid >> 2, s4 = (tid & 3) * 16;
    const u16* vp = QKV + (size_t)(b * SEQ + kt * 64 + r) * N_QKV + 2 * D_MODEL + h * 64 + s4;
    *(short8*)&T[r * 72 + s4]     = *(const short8*)&vp[0];
    *(short8*)&T[r * 72 + s4 + 8] = *(const short8*)&vp[8];
    __syncthreads();
    u16 tmp[16];
    #pragma unroll
    for (int i = 0; i < 16; i++) tmp[i] = T[(s4 + i) * 72 + r];
    u16* op = Vtg + ((size_t)bh * 64 + r) * SEQ + kt * 64 + s4;
    *(short8*)&op[0] = *(short8*)&tmp[0];
    *(short8*)&op[8] = *(short8*)&tmp[8];
}

// ---------------------------------------------------------------------------
// Shared macros for the 4-phase 8-wave GEMM skeleton (r5-proven).
// ---------------------------------------------------------------------------
#define G256_BAR   __builtin_amdgcn_s_barrier()
#define G256_LGKM(n) { asm volatile("s_waitcnt lgkmcnt(" #n ")" ::: "memory"); \
                       __builtin_amdgcn_sched_barrier(0); }

// ---------------------------------------------------------------------------
// gemm_qkv: 256x192 tile (tail-free: 16x32 = 512 blocks = exactly 2 rounds),
// BK=64, 8 waves (2M x 4N), 112 KiB LDS, 4-phase read-one-phase-ahead.
// (unchanged from round 5/6 — passing + fastest known for the QKV GEMM)
// ---------------------------------------------------------------------------
#define GQ_STAGE_A(bb, ca, kq) \
    async_copy16(pAc + (size_t)(ca) * 64 * K + (kq), \
                 &lds[(bb) * 28672 + (ca) * 4096 + stw]);

#define GQ_STAGE_B(bb, cb, kq) \
    async_copy16(pBc + (size_t)(cb) * 64 * K + (kq), \
                 &lds[(bb) * 28672 + 16384 + (cb) * 4096 + stw]);

#define GQ_LDA4(dst, bb, mi0) { \
    const int _b = (bb) * 28672 + wm * 8192; \
    _Pragma("unroll") \
    for (int mi = 0; mi < 4; mi++) { \
        const int _r = _b + (((mi0) + mi) * 16 + l16) * 64; \
        dst[mi * 2]     = *(const short8*)&lds[_r + col0]; \
        dst[mi * 2 + 1] = *(const short8*)&lds[_r + col1]; \
    } }

#define GQ_LDB2(dst, bb, ni0) { \
    const int _b = (bb) * 28672 + 16384 + wn * 3072; \
    _Pragma("unroll") \
    for (int ni = 0; ni < 2; ni++) { \
        const int _r = _b + (((ni0) + ni) * 16 + l16) * 64; \
        dst[ni * 2]     = *(const short8*)&lds[_r + col0]; \
        dst[ni * 2 + 1] = *(const short8*)&lds[_r + col1]; \
    } }

#define GQ_LDB1(dst, bb, ni0) { \
    const int _b = (bb) * 28672 + 16384 + wn * 3072; \
    const int _r = _b + ((ni0) * 16 + l16) * 64; \
    dst[0] = *(const short8*)&lds[_r + col0]; \
    dst[1] = *(const short8*)&lds[_r + col1]; }

// swapped operands: mfma(b, a) -> C col(l16)=m-row, row(quad*4+r)=n-col
#define GQ_MMA8(av, bv, MI0, NI0) { \
    _Pragma("unroll") \
    for (int mi = 0; mi < 4; mi++) \
    _Pragma("unroll") \
    for (int ni = 0; ni < 2; ni++) { \
        acc[(MI0) + mi][(NI0) + ni] = __builtin_amdgcn_mfma_f32_16x16x32_bf16( \
            bv[ni * 2],     av[mi * 2],     acc[(MI0) + mi][(NI0) + ni], 0, 0, 0); \
        acc[(MI0) + mi][(NI0) + ni] = __builtin_amdgcn_mfma_f32_16x16x32_bf16( \
            bv[ni * 2 + 1], av[mi * 2 + 1], acc[(MI0) + mi][(NI0) + ni], 0, 0, 0); \
    } }

#define GQ_MMA4(av, bv, MI0) { \
    _Pragma("unroll") \
    for (int mi = 0; mi < 4; mi++) { \
        acc[(MI0) + mi][2] = __builtin_amdgcn_mfma_f32_16x16x32_bf16( \
            bv[0], av[mi * 2],     acc[(MI0) + mi][2], 0, 0, 0); \
        acc[(MI0) + mi][2] = __builtin_amdgcn_mfma_f32_16x16x32_bf16( \
            bv[1], av[mi * 2 + 1], acc[(MI0) + mi][2], 0, 0, 0); \
    } }

template <typename OT>
__global__ __launch_bounds__(512, 2) void gemm_qkv(
    const u16* __restrict__ A, const u16* __restrict__ Bt,
    const float* __restrict__ bias, OT* __restrict__ C,
    int M, int N, int K)   // requires K >= 192 (NKT >= 3)
{
    __shared__ u16 lds[57344];   // 112 KiB = 2 buf x 7 chunks x 8 KB
    const int tid = threadIdx.x;
    const int w = tid >> 6, lane = tid & 63;
    const int l16 = lane & 15, quad = lane >> 4;
    const int wm = w >> 2, wn = w & 3;

    // XCD-aware swizzle (nwg % 8 == 0): contiguous tile chunk per XCD, x-fast
    const int nwgx = gridDim.x;
    const int nwg = nwgx * gridDim.y;
    const int lin = blockIdx.y * nwgx + blockIdx.x;
    const int cpx = nwg >> 3;
    const int swz = (lin & 7) * cpx + (lin >> 3);
    const int bn = (swz % nwgx) * 192, bm = (swz / nwgx) * 256;

    // staging: thread's 16B slot d in an 8 KB chunk; source = swz(d)
    const int d = tid * 16;
    const int s = d ^ (((d >> 7) & 7) << 4);
    const int r = s >> 7;              // row in chunk (0..63)
    const int c = (s & 127) >> 1;      // col element (0..63)
    const u16* pAc = A  + (size_t)(bm + r) * K + c;
    const u16* pBc = Bt + (size_t)(bn + r) * K + c;
    const int stw = w * 512;           // wave's slot base within a chunk (u16)

    // swizzled ds_read col offsets (u16), kc = 0 / 1
    const int xm = (l16 & 7) << 3;
    const int col0 = (quad * 8) ^ xm;
    const int col1 = (32 + quad * 8) ^ xm;

    floatx4 acc[8][3];
    #pragma unroll
    for (int i = 0; i < 8; i++)
        #pragma unroll
        for (int j = 0; j < 3; j++) acc[i][j] = (floatx4){0.f, 0.f, 0.f, 0.f};

    // prologue: A(0) c0-3, B(0) c0-2 -> buf0; B(1) c0-2 -> buf1. 10 issues;
    // vmcnt(3) = A(0)+B(0) landed (leaves B(1)); then pre-read a0,b0 of kt=0.
    GQ_STAGE_A(0, 0, 0); GQ_STAGE_A(0, 1, 0); GQ_STAGE_A(0, 2, 0); GQ_STAGE_A(0, 3, 0);
    GQ_STAGE_B(0, 0, 0); GQ_STAGE_B(0, 1, 0); GQ_STAGE_B(0, 2, 0);
    GQ_STAGE_B(1, 0, 64); GQ_STAGE_B(1, 1, 64); GQ_STAGE_B(1, 2, 64);
    asm volatile("s_waitcnt vmcnt(3)" ::: "memory");
    __syncthreads();

    short8 a0[8], a1[8], b0[4], b1[2];
    GQ_LDA4(a0, 0, 0);
    GQ_LDB2(b0, 0, 0);

    const int NKT = K >> 6;
    for (int kt = 0; kt < NKT; ++kt) {
        const int buf = kt & 1, nb = buf ^ 1;
        const int kqA = (kt + 1) << 6, kqB = (kt + 2) << 6;
        const bool st1 = (kt + 1 < NKT), st2 = (kt + 2 < NKT);

        // ---- ph0: read b1(kt); stage A c0,c1(kt+1); MMA Q00(a0,b0)
        GQ_LDB1(b1, buf, 2);
        if (st1) { GQ_STAGE_A(nb, 0, kqA); GQ_STAGE_A(nb, 1, kqA); }
        G256_BAR; G256_LGKM(2);
        __builtin_amdgcn_s_setprio(1); GQ_MMA8(a0, b0, 0, 0);
        __builtin_amdgcn_s_setprio(0); G256_BAR;

        // ---- ph1: read a1(kt); stage A c2,c3(kt+1); MMA Q01(a0,b1)
        GQ_LDA4(a1, buf, 4);
        if (st1) { GQ_STAGE_A(nb, 2, kqA); GQ_STAGE_A(nb, 3, kqA); }
        G256_BAR; G256_LGKM(8);
        __builtin_amdgcn_s_setprio(1); GQ_MMA4(a0, b1, 0);
        __builtin_amdgcn_s_setprio(0); G256_BAR;

        // ---- ph2: stage B c0,c1(kt+2); MMA Q10(a1,b0)
        if (st2) { GQ_STAGE_B(buf, 0, kqB); GQ_STAGE_B(buf, 1, kqB); }
        G256_BAR; G256_LGKM(0);
        __builtin_amdgcn_s_setprio(1); GQ_MMA8(a1, b0, 4, 0);
        __builtin_amdgcn_s_setprio(0); G256_BAR;

        // ---- ph3: stage B c2(kt+2); vmcnt; pre-read a0,b0(kt+1);
        //      MMA Q11(a1,b1) touches neither a0 nor b0 -> overlaps DS drain
        if (st2) { GQ_STAGE_B(buf, 2, kqB); }
        if (st1) {
            if (st2) { asm volatile("s_waitcnt vmcnt(3)" ::: "memory"); }
            else     { asm volatile("s_waitcnt vmcnt(0)" ::: "memory"); }
            __builtin_amdgcn_sched_barrier(0);
            GQ_LDA4(a0, nb, 0);
            GQ_LDB2(b0, nb, 0);
        }
        G256_BAR;
        __builtin_amdgcn_s_setprio(1); GQ_MMA4(a1, b1, 4);
        __builtin_amdgcn_s_setprio(0); G256_BAR;
    }

    // epilogue: lane holds 4 consecutive cols; mi-outer so each 64B line
    // is completed by back-to-back stores
    float4 bi[3];
    #pragma unroll
    for (int ni = 0; ni < 3; ni++)
        bi[ni] = *(const float4*)&bias[bn + wn * 48 + ni * 16 + quad * 4];
    #pragma unroll
    for (int mi = 0; mi < 8; mi++) {
        const int row = bm + wm * 128 + mi * 16 + l16;
        #pragma unroll
        for (int ni = 0; ni < 3; ni++) {
            const int col = bn + wn * 48 + ni * 16 + quad * 4;
            const float v0 = acc[mi][ni][0] + bi[ni].x;
            const float v1 = acc[mi][ni][1] + bi[ni].y;
            const float v2 = acc[mi][ni][2] + bi[ni].z;
            const float v3 = acc[mi][ni][3] + bi[ni].w;
            if constexpr (sizeof(OT) == 2) {
                u16 o[4] = {f2u(v0), f2u(v1), f2u(v2), f2u(v3)};
                *(short4v*)&((u16*)C)[(size_t)row * N + col] = *(short4v*)o;
            } else {
                float4 fv = {v0, v1, v2, v3};
                *(float4*)&C[(size_t)row * N + col] = fv;
            }
        }
    }
}

// ---------------------------------------------------------------------------
// gemm_out: 256x128 tile on the same 4-phase skeleton. Grid for the output
// GEMM (N=1024): 8 x 32 = 256 blocks = EXACTLY 1 dispatch round (vs 512
// blocks / 2 rounds of the old 128^2 m97 kernel). BK=64, 8 waves (2M x 4N,
// wave = 128x32), 96 KiB LDS (per buf: A 4 chunks + B 2 chunks x 8 KB).
//
// Per K-tile kt (quadrants Q00(a0,bb0) Q01(a0,bb1) Q10(a1,bb0) Q11(a1,bb1)):
//  ph0: read bb1(kt)[2]; stage A c0,c1(kt+1)->nb; BAR; lgkm(2); MMA Q00 [8]
//  ph1: read a1(kt)[8];  stage A c2,c3(kt+1)->nb; BAR; lgkm(8); MMA Q01 [8]
//  ph2: stage B c0,c1(kt+2)->buf;                 BAR; lgkm(0); MMA Q10 [8]
//  ph3: vmcnt(2); pre-read a0[8],bb0[2](kt+1);    BAR;          MMA Q11 [8]
// vmcnt ledger (steady): in-flight at ph3 = B(kt+1)[2, kt-1 ph2] +
// A(kt+1)[4, kt ph0/1] + B(kt+2)[2, kt ph2] = 8 -> vmcnt(2) drains
// everything of kt+1, leaves B(kt+2). Region liveness traced as gemm_qkv.
// ---------------------------------------------------------------------------
#define GO_STAGE_A(bb, ca, kq) \
    async_copy16(pAc + (size_t)(ca) * 64 * K + (kq), \
                 &lds[(bb) * 24576 + (ca) * 4096 + stw]);

#define GO_STAGE_B(bb, cb, kq) \
    async_copy16(pBc + (size_t)(cb) * 64 * K + (kq), \
                 &lds[(bb) * 24576 + 16384 + (cb) * 4096 + stw]);

#define GO_LDA4(dst, bb, mi0) { \
    const int _b = (bb) * 24576 + wm * 8192; \
    _Pragma("unroll") \
    for (int mi = 0; mi < 4; mi++) { \
        const int _r = _b + (((mi0) + mi) * 16 + l16) * 64; \
        dst[mi * 2]     = *(const short8*)&lds[_r + col0]; \
        dst[mi * 2 + 1] = *(const short8*)&lds[_r + col1]; \
    } }

#define GO_LDB1(dst, bb, ni) { \
    const int _b = (bb) * 24576 + 16384; \
    const int _r = _b + (wn * 32 + (ni) * 16 + l16) * 64; \
    dst[0] = *(const short8*)&lds[_r + col0]; \
    dst[1] = *(const short8*)&lds[_r + col1]; }

#define GO_MMA(av, bv, MI0, NI) { \
    _Pragma("unroll") \
    for (int mi = 0; mi < 4; mi++) { \
        acc[(MI0) + mi][NI] = __builtin_amdgcn_mfma_f32_16x16x32_bf16( \
            bv[0], av[mi * 2],     acc[(MI0) + mi][NI], 0, 0, 0); \
        acc[(MI0) + mi][NI] = __builtin_amdgcn_mfma_f32_16x16x32_bf16( \
            bv[1], av[mi * 2 + 1], acc[(MI0) + mi][NI], 0, 0, 0); \
    } }

__global__ __launch_bounds__(512, 2) void gemm_out(
    const u16* __restrict__ A, const u16* __restrict__ Bt,
    const float* __restrict__ bias, float* __restrict__ C,
    int M, int N, int K)   // requires K >= 192 (NKT >= 3)
{
    __shared__ u16 lds[49152];   // 96 KiB = 2 buf x 6 chunks x 8 KB
    const int tid = threadIdx.x;
    const int w = tid >> 6, lane = tid & 63;
    const int l16 = lane & 15, quad = lane >> 4;
    const int wm = w >> 2, wn = w & 3;

    // XCD-aware swizzle (nwg % 8 == 0)
    const int nwgx = gridDim.x;
    const int nwg = nwgx * gridDim.y;
    const int lin = blockIdx.y * nwgx + blockIdx.x;
    const int cpx = nwg >> 3;
    const int swz = (lin & 7) * cpx + (lin >> 3);
    const int bn = (swz % nwgx) * 128, bm = (swz / nwgx) * 256;

    // staging: thread's 16B slot d in an 8 KB chunk; source = swz(d)
    const int d = tid * 16;
    const int s = d ^ (((d >> 7) & 7) << 4);
    const int r = s >> 7;
    const int c = (s & 127) >> 1;
    const u16* pAc = A  + (size_t)(bm + r) * K + c;
    const u16* pBc = Bt + (size_t)(bn + r) * K + c;
    const int stw = w * 512;

    const int xm = (l16 & 7) << 3;
    const int col0 = (quad * 8) ^ xm;
    const int col1 = (32 + quad * 8) ^ xm;

    floatx4 acc[8][2];
    #pragma unroll
    for (int i = 0; i < 8; i++)
        #pragma unroll
        for (int j = 0; j < 2; j++) acc[i][j] = (floatx4){0.f, 0.f, 0.f, 0.f};

    // prologue: A(0) c0-3, B(0) c0-1 -> buf0; B(1) c0-1 -> buf1. 8 issues;
    // vmcnt(2) = A(0)+B(0) landed (leaves B(1)); pre-read a0,bb0 of kt=0.
    GO_STAGE_A(0, 0, 0); GO_STAGE_A(0, 1, 0); GO_STAGE_A(0, 2, 0); GO_STAGE_A(0, 3, 0);
    GO_STAGE_B(0, 0, 0); GO_STAGE_B(0, 1, 0);
    GO_STAGE_B(1, 0, 64); GO_STAGE_B(1, 1, 64);
    asm volatile("s_waitcnt vmcnt(2)" ::: "memory");
    __syncthreads();

    short8 a0[8], a1[8], bb0[2], bb1[2];
    GO_LDA4(a0, 0, 0);
    GO_LDB1(bb0, 0, 0);

    const int NKT = K >> 6;
    for (int kt = 0; kt < NKT; ++kt) {
        const int buf = kt & 1, nb = buf ^ 1;
        const int kqA = (kt + 1) << 6, kqB = (kt + 2) << 6;
        const bool st1 = (kt + 1 < NKT), st2 = (kt + 2 < NKT);

        // ---- ph0: read bb1(kt); stage A c0,c1(kt+1); MMA Q00(a0,bb0)
        GO_LDB1(bb1, buf, 1);
        if (st1) { GO_STAGE_A(nb, 0, kqA); GO_STAGE_A(nb, 1, kqA); }
        G256_BAR; G256_LGKM(2);
        __builtin_amdgcn_s_setprio(1); GO_MMA(a0, bb0, 0, 0);
        __builtin_amdgcn_s_setprio(0); G256_BAR;

        // ---- ph1: read a1(kt); stage A c2,c3(kt+1); MMA Q01(a0,bb1)
        GO_LDA4(a1, buf, 4);
        if (st1) { GO_STAGE_A(nb, 2, kqA); GO_STAGE_A(nb, 3, kqA); }
        G256_BAR; G256_LGKM(8);
        __builtin_amdgcn_s_setprio(1); GO_MMA(a0, bb1, 0, 1);
        __builtin_amdgcn_s_setprio(0); G256_BAR;

        // ---- ph2: stage B c0,c1(kt+2); MMA Q10(a1,bb0)
        if (st2) { GO_STAGE_B(buf, 0, kqB); GO_STAGE_B(buf, 1, kqB); }
        G256_BAR; G256_LGKM(0);
        __builtin_amdgcn_s_setprio(1); GO_MMA(a1, bb0, 4, 0);
        __builtin_amdgcn_s_setprio(0); G256_BAR;

        // ---- ph3: vmcnt; pre-read a0,bb0(kt+1); MMA Q11(a1,bb1)
        if (st1) {
            if (st2) { asm volatile("s_waitcnt vmcnt(2)" ::: "memory"); }
            else     { asm volatile("s_waitcnt vmcnt(0)" ::: "memory"); }
            __builtin_amdgcn_sched_barrier(0);
            GO_LDA4(a0, nb, 0);
            GO_LDB1(bb0, nb, 0);
        }
        G256_BAR;
        __builtin_amdgcn_s_setprio(1); GO_MMA(a1, bb1, 4, 1);
        __builtin_amdgcn_s_setprio(0); G256_BAR;
    }

    // epilogue: lane holds 4 consecutive cols (float4 stores)
    float4 bi[2];
    #pragma unroll
    for (int ni = 0; ni < 2; ni++)
        bi[ni] = *(const float4*)&bias[bn + wn * 32 + ni * 16 + quad * 4];
    #pragma unroll
    for (int mi = 0; mi < 8; mi++) {
        const int row = bm + wm * 128 + mi * 16 + l16;
        #pragma unroll
        for (int ni = 0; ni < 2; ni++) {
            const int col = bn + wn * 32 + ni * 16 + quad * 4;
            float4 fv = {acc[mi][ni][0] + bi[ni].x, acc[mi][ni][1] + bi[ni].y,
                         acc[mi][ni][2] + bi[ni].z, acc[mi][ni][3] + bi[ni].w};
            *(float4*)&C[(size_t)row * N + col] = fv;
        }
    }
}

// ---------------------------------------------------------------------------
// attn_mfma v5: 40 KiB LDS -> 4 blocks/CU (grid = 1024 = exactly 4/CU
// co-resident). Per tile: QK^T for BOTH m first (z[2][4] in regs; kf dies
// before vf loads -> VGPR-neutral), then per-m: softmax -> per-wave 16-row
// Ps slice (8 KB total, 8B-block XOR swizzle blk^=2*(l16&7)) -> p-read ->
// lsum+PV. In-wave ds_write->ds_read ordering (same guarantee as before).
// ---------------------------------------------------------------------------
__global__ __launch_bounds__(256, 4) void attn_mfma(
    const u16* __restrict__ QKV, const u16* __restrict__ Vtg, u16* __restrict__ ctx)
{
    __shared__ u16 Ks[2][64 * 64];   // [key][d], chunk-swizzled   16 KB
    __shared__ u16 Vs[2][64 * 64];   // [d][key], chunk-swizzled   16 KB
    __shared__ u16 Ps[4 * 16 * 64];  // per-wave 16-row P slice     8 KB

    const int bh = blockIdx.x;
    const int qt = (int)(gridDim.y - 1) - (int)blockIdx.y;   // long blocks first
    const int b = bh >> 4, h = bh & 15;
    const int tid = threadIdx.x;
    const int w = tid >> 6, lane = tid & 63;
    const int l16 = lane & 15, quad = lane >> 4;

    // staging geometry: 512 chunks of 16B per 8KB tile; thread handles f, f+256
    const int r0 = tid >> 3,        c0 = tid & 7;          // f = tid
    const int r1 = (256 + tid) >> 3, c1 = tid & 7;         // f = 256+tid
    const int sw0 = c0 ^ (r0 & 7), sw1 = c1 ^ (r1 & 7);

    // Q fragments (MFMA B-operand): lane l16 <-> q-row, k = quad*8+j
    short8 q[2][2];
    #pragma unroll
    for (int m = 0; m < 2; m++) {
        const u16* qp = QKV + (size_t)(b * SEQ + qt * 128 + w * 32 + m * 16 + l16) * N_QKV + h * 64;
        q[m][0] = *(const short8*)&qp[quad * 8];
        q[m][1] = *(const short8*)&qp[32 + quad * 8];
    }

    // ones fragment for MFMA row-sum (bf16 1.0 = 0x3F80)
    short8 ones8;
    #pragma unroll
    for (int i = 0; i < 8; i++) ones8[i] = (short)0x3F80;

    floatx4 O[2][4];               // O^T: rows d, col qrow=l16
    floatx4 lsum[2];               // row-sum accumulator (all regs = sum)
    #pragma unroll
    for (int m = 0; m < 2; m++) {
        lsum[m] = (floatx4){0.f, 0.f, 0.f, 0.f};
        #pragma unroll
        for (int i = 0; i < 4; i++) O[m][i] = (floatx4){0.f, 0.f, 0.f, 0.f};
    }

    const int nkt = 2 * qt + 2;
    const int qrow_w_max = qt * 128 + w * 32 + 31;

    const size_t kbase = (size_t)(b * SEQ) * N_QKV + D_MODEL + h * 64;
    const size_t vbase = (size_t)bh * 64 * SEQ;

    // running prefetch pointers (advance by one K-tile per iteration)
    const u16* kpa = QKV + kbase + (size_t)r0 * N_QKV + c0 * 8;
    const u16* kpb = QKV + kbase + (size_t)r1 * N_QKV + c1 * 8;
    const u16* vpa = Vtg + vbase + (size_t)r0 * SEQ + c0 * 8;
    const u16* vpb = Vtg + vbase + (size_t)r1 * SEQ + c1 * 8;

    // prologue: tile 0 -> buf 0
    {
        float4 ka = *(const float4*)kpa;
        float4 kb = *(const float4*)kpb;
        float4 va = *(const float4*)vpa;
        float4 vb = *(const float4*)vpb;
        *(float4*)&Ks[0][r0 * 64 + sw0 * 8] = ka;
        *(float4*)&Ks[0][r1 * 64 + sw1 * 8] = kb;
        *(float4*)&Vs[0][r0 * 64 + sw0 * 8] = va;
        *(float4*)&Vs[0][r1 * 64 + sw1 * 8] = vb;
    }
    kpa += (size_t)64 * N_QKV; kpb += (size_t)64 * N_QKV;
    vpa += 64; vpb += 64;
    __syncthreads();

    const int e7 = l16 & 7;
    const int pbase = w * 1024 + l16 * 64;   // wave slice, row = l16

    for (int kt = 0; kt < nkt; kt++) {
        const int buf = kt & 1;
        const bool pre = (kt + 1 < nkt);
        float4 ka, kb, va, vb;
        if (pre) {
            ka = *(const float4*)kpa;
            kb = *(const float4*)kpb;
            va = *(const float4*)vpa;
            vb = *(const float4*)vpb;
            kpa += (size_t)64 * N_QKV; kpb += (size_t)64 * N_QKV;
            vpa += 64; vpb += 64;
        }

        if (kt * 64 <= qrow_w_max) {
            // K fragments, swizzle-decoded
            short8 kf[4][2];
            #pragma unroll
            for (int ns = 0; ns < 4; ns++) {
                const int rr = ns * 16 + l16, rs = rr & 7;
                kf[ns][0] = *(short8*)&Ks[buf][rr * 64 + (quad ^ rs) * 8];
                kf[ns][1] = *(short8*)&Ks[buf][rr * 64 + ((4 + quad) ^ rs) * 8];
            }
            const bool needMask = (kt * 64 + 63 > qt * 128 + w * 32);

            // QK^T for both m (z in regs; kf dead afterwards)
            floatx4 z[2][4];
            __builtin_amdgcn_s_setprio(1);
            #pragma unroll
            for (int m = 0; m < 2; m++)
                #pragma unroll
                for (int ns = 0; ns < 4; ns++) {
                    floatx4 t = (floatx4){0.f, 0.f, 0.f, 0.f};
                    t = __builtin_amdgcn_mfma_f32_16x16x32_bf16(kf[ns][0], q[m][0], t, 0, 0, 0);
                    t = __builtin_amdgcn_mfma_f32_16x16x32_bf16(kf[ns][1], q[m][1], t, 0, 0, 0);
                    z[m][ns] = t;
                }
            __builtin_amdgcn_s_setprio(0);

            // V fragments
            short8 vf[4][2];
            #pragma unroll
            for (int ds = 0; ds < 4; ds++) {
                const int rr = ds * 16 + l16, rs = rr & 7;
                vf[ds][0] = *(short8*)&Vs[buf][rr * 64 + (quad ^ rs) * 8];
                vf[ds][1] = *(short8*)&Vs[buf][rr * 64 + ((4 + quad) ^ rs) * 8];
            }

            // per-m: softmax -> slice write -> p read -> lsum + PV
            #pragma unroll
            for (int m = 0; m < 2; m++) {
                const int qrow_g = qt * 128 + w * 32 + m * 16 + l16;
                #pragma unroll
                for (int ns = 0; ns < 4; ns++) {
                    u16 pk[4];
                    #pragma unroll
                    for (int r = 0; r < 4; r++) {
                        float s = z[m][ns][r];
                        const int key = kt * 64 + ns * 16 + quad * 4 + r;
                        if (needMask && key > qrow_g) s = -INFINITY;
                        float p = __builtin_amdgcn_exp2f(s - EXP2_OFF);
                        pk[r] = f2u(p);
                    }
                    // 8B block (ns*4+quad) XOR-swizzled by 2*e7
                    *(short4v*)&Ps[pbase + (((ns * 4 + quad) ^ (2 * e7)) << 2)] = *(short4v*)pk;
                }
                short8 p0 = *(short8*)&Ps[pbase + ((quad ^ e7) << 3)];
                short8 p1 = *(short8*)&Ps[pbase + (((4 + quad) ^ e7) << 3)];
                __builtin_amdgcn_s_setprio(1);
                lsum[m] = __builtin_amdgcn_mfma_f32_16x16x32_bf16(ones8, p0, lsum[m], 0, 0, 0);
                lsum[m] = __builtin_amdgcn_mfma_f32_16x16x32_bf16(ones8, p1, lsum[m], 0, 0, 0);
                #pragma unroll
                for (int ds = 0; ds < 4; ds++) {
                    O[m][ds] = __builtin_amdgcn_mfma_f32_16x16x32_bf16(vf[ds][0], p0, O[m][ds], 0, 0, 0);
                    O[m][ds] = __builtin_amdgcn_mfma_f32_16x16x32_bf16(vf[ds][1], p1, O[m][ds], 0, 0, 0);
                }
                __builtin_amdgcn_s_setprio(0);
            }
        }

        if (pre) {
            const int nb = buf ^ 1;
            *(float4*)&Ks[nb][r0 * 64 + sw0 * 8] = ka;
            *(float4*)&Ks[nb][r1 * 64 + sw1 * 8] = kb;
            *(float4*)&Vs[nb][r0 * 64 + sw0 * 8] = va;
            *(float4*)&Vs[nb][r1 * 64 + sw1 * 8] = vb;
        }
        __syncthreads();
    }

    // epilogue: O^T / l -> ctx[qrow][d], packed 8 B stores
    #pragma unroll
    for (int m = 0; m < 2; m++) {
        const float inv = 1.0f / lsum[m][0];
        const size_t base = (size_t)(b * SEQ + qt * 128 + w * 32 + m * 16 + l16) * D_MODEL + h * 64;
        #pragma unroll
        for (int ds = 0; ds < 4; ds++) {
            u16 o[4];
            #pragma unroll
            for (int r = 0; r < 4; r++) o[r] = f2u(O[m][ds][r] * inv);
            *(short4v*)&ctx[base + ds * 16 + quad * 4] = *(short4v*)o;
        }
    }
}

// ---------------------------------------------------------------------------
extern "C" void kernel_launch(void* const* d_in, const int* in_sizes, int n_in,
                              void* d_out, int out_size, void* d_ws, size_t ws_size,
                              hipStream_t stream) {
    const float* x  = (const float*)d_in[0];
    const float* Wq = (const float*)d_in[1];
    const float* bq = (const float*)d_in[2];
    const float* Wk = (const float*)d_in[3];
    const float* bk = (const float*)d_in[4];
    const float* Wv = (const float*)d_in[5];
    const float* bv = (const float*)d_in[6];
    const float* Wo = (const float*)d_in[7];
    const float* bo = (const float*)d_in[8];
    float* out = (float*)d_out;

    // workspace (bytes): total 0x5840000 = 92.3 MB (Vtg overlays dead xb)
    char* ws = (char*)d_ws;
    float* biasp = (float*)ws;                       // 16 KB
    u16*   Wpt   = (u16*)(ws + 0x10000);             // 6 MB  [3072][1024]
    u16*   Wot   = (u16*)(ws + 0x620000);            // 2 MB  [1024][1024]
    u16*   xb    = (u16*)(ws + 0x840000);            // 16 MB [8192][1024]
    u16*   Vtg   = xb;                               // overlay: xb dead after QKV GEMM
    u16*   QKV   = (u16*)(ws + 0x1840000);           // 48 MB [8192][3072]
    u16*   ctx   = (u16*)(ws + 0x4840000);           // 16 MB [8192][1024]

    prep<<<5121, 256, 0, stream>>>(x, Wq, Wk, Wv, Wo, bq, bk, bv, bo,
                                   xb, Wpt, Wot, biasp);

    gemm_qkv<u16><<<dim3(N_QKV / 192, M_ROWS / 256), 512, 0, stream>>>(
        xb, Wpt, biasp, QKV, M_ROWS, N_QKV, D_MODEL);

    vtrans<<<dim3(64, 32), 256, 0, stream>>>(QKV, Vtg);

    attn_mfma<<<dim3(BATCH * NH, SEQ / 128), 256, 0, stream>>>(QKV, Vtg, ctx);

    gemm_out<<<dim3(D_MODEL / 128, M_ROWS / 256), 512, 0, stream>>>(
        ctx, Wot, biasp + N_QKV, out, M_ROWS, D_MODEL, D_MODEL);
}

// Round 8
// 277.743 us; speedup vs baseline: 1.6060x; 1.6060x over previous
//
#include <hip/hip_runtime.h>
#include <hip/hip_bf16.h>

typedef unsigned short u16;
typedef __attribute__((ext_vector_type(8))) short short8;   // 8 bf16 = 4 VGPRs
typedef __attribute__((ext_vector_type(4))) short short4v;  // 4 bf16 = 8 B
typedef __attribute__((ext_vector_type(4))) float floatx4;  // MFMA C/D

#define D_MODEL 1024
#define NH 16
#define SEQ 2048
#define BATCH 4
#define M_ROWS 8192
#define N_QKV 3072

// Q-path prescale: 1/sqrt(64) * log2(e) so softmax is exp2(s - 8*log2e)
#define QSCALE 0.18033688011112042f
#define EXP2_OFF 11.541560327111707f   // 8 * log2(e)

__device__ __forceinline__ u16 f2u(float f) {
    __hip_bfloat16 h = __float2bfloat16(f);
    u16 u; __builtin_memcpy(&u, &h, 2); return u;
}

// async global->LDS, 16B per lane; dest = wave-uniform base + lane*16
__device__ __forceinline__ void async_copy16(const u16* g, u16* l) {
    __builtin_amdgcn_global_load_lds(
        (const __attribute__((address_space(1))) unsigned int*)(g),
        (__attribute__((address_space(3))) unsigned int*)(l),
        16, 0, 0);
}

// ---------------------------------------------------------------------------
// prep (one launch): blocks 0..4095 convert x->bf16; 4096..5119 transpose
// weights (Wq pre-scaled by QSCALE); block 5120 packs biases.
// ---------------------------------------------------------------------------
__global__ __launch_bounds__(256) void prep(
    const float* __restrict__ x,
    const float* __restrict__ Wq, const float* __restrict__ Wk,
    const float* __restrict__ Wv, const float* __restrict__ Wo,
    const float* __restrict__ bq, const float* __restrict__ bk,
    const float* __restrict__ bv, const float* __restrict__ bo,
    u16* __restrict__ xb, u16* __restrict__ Wpt, u16* __restrict__ Wot,
    float* __restrict__ biasp)
{
    __shared__ u16 T[64 * 72];
    const int tid = threadIdx.x;
    const int blk = blockIdx.x;

    if (blk < 4096) {                       // x -> bf16
        size_t i = ((size_t)blk * 256 + tid) * 8;
        float4 f0 = *(const float4*)&x[i];
        float4 f1 = *(const float4*)&x[i + 4];
        u16 t[8] = {f2u(f0.x), f2u(f0.y), f2u(f0.z), f2u(f0.w),
                    f2u(f1.x), f2u(f1.y), f2u(f1.z), f2u(f1.w)};
        *(short8*)&xb[i] = *(short8*)t;
        return;
    }
    if (blk == 5120) {                      // biases
        #pragma unroll
        for (int j = 0; j < 16; j++) {
            int idx = j * 256 + tid;
            float v;
            if (idx < 1024)      v = bq[idx] * QSCALE;
            else if (idx < 2048) v = bk[idx - 1024];
            else if (idx < 3072) v = bv[idx - 2048];
            else                 v = bo[idx - 3072];
            biasp[idx] = v;
        }
        return;
    }
    const int wb = blk - 4096;              // 0..1023: weight transpose
    const int r = tid >> 2, s4 = (tid & 3) * 16;
    if (wb < 768) {
        int sel = wb / 256, rem = wb % 256;
        int h = rem >> 4, ktile = rem & 15;
        const float* W = (sel == 0) ? Wq : ((sel == 1) ? Wk : Wv);
        const float scale = (sel == 0) ? QSCALE : 1.0f;
        const float* src = W + ((size_t)h * 1024 + ktile * 64 + r) * 64 + s4;
        #pragma unroll
        for (int i = 0; i < 16; i++) T[(s4 + i) * 72 + r] = f2u(src[i] * scale);
        __syncthreads();
        u16 tmp[16];
        #pragma unroll
        for (int i = 0; i < 16; i++) tmp[i] = T[r * 72 + s4 + i];
        u16* dst = Wpt + ((size_t)sel * 1024 + h * 64 + r) * 1024 + ktile * 64 + s4;
        *(short8*)&dst[0] = *(short8*)&tmp[0];
        *(short8*)&dst[8] = *(short8*)&tmp[8];
    } else {
        int rem = wb - 768;
        int nt = rem >> 4, kt2 = rem & 15;
        const float* src = Wo + ((size_t)kt2 * 64 + r) * 1024 + nt * 64 + s4;
        #pragma unroll
        for (int i = 0; i < 16; i++) T[(s4 + i) * 72 + r] = f2u(src[i]);
        __syncthreads();
        u16 tmp[16];
        #pragma unroll
        for (int i = 0; i < 16; i++) tmp[i] = T[r * 72 + s4 + i];
        u16* dst = Wot + ((size_t)nt * 64 + r) * 1024 + kt2 * 64 + s4;
        *(short8*)&dst[0] = *(short8*)&tmp[0];
        *(short8*)&dst[8] = *(short8*)&tmp[8];
    }
}

// ---------------------------------------------------------------------------
// vtrans: V slice of QKV -> Vtg[bh][d][key] via LDS tile.
// ---------------------------------------------------------------------------
__global__ __launch_bounds__(256) void vtrans(const u16* __restrict__ QKV,
                                              u16* __restrict__ Vtg) {
    __shared__ u16 T[64 * 72];
    const int bh = blockIdx.x, kt = blockIdx.y;
    const int b = bh >> 4, h = bh & 15;
    const int tid = threadIdx.x;
    const int r = tid >> 2, s4 = (tid & 3) * 16;
    const u16* vp = QKV + (size_t)(b * SEQ + kt * 64 + r) * N_QKV + 2 * D_MODEL + h * 64 + s4;
    *(short8*)&T[r * 72 + s4]     = *(const short8*)&vp[0];
    *(short8*)&T[r * 72 + s4 + 8] = *(const short8*)&vp[8];
    __syncthreads();
    u16 tmp[16];
    #pragma unroll
    for (int i = 0; i < 16; i++) tmp[i] = T[(s4 + i) * 72 + r];
    u16* op = Vtg + ((size_t)bh * 64 + r) * SEQ + kt * 64 + s4;
    *(short8*)&op[0] = *(short8*)&tmp[0];
    *(short8*)&op[8] = *(short8*)&tmp[8];
}

// ---------------------------------------------------------------------------
// Shared macros for the 4-phase 8-wave GEMM skeleton (r5-proven).
// ---------------------------------------------------------------------------
#define G256_BAR   __builtin_amdgcn_s_barrier()
#define G256_LGKM(n) { asm volatile("s_waitcnt lgkmcnt(" #n ")" ::: "memory"); \
                       __builtin_amdgcn_sched_barrier(0); }

// ---------------------------------------------------------------------------
// gemm_qkv: 256x192 tile (tail-free: 16x32 = 512 blocks = exactly 2 rounds),
// BK=64, 8 waves (2M x 4N), 112 KiB LDS, 4-phase read-one-phase-ahead.
// (unchanged — passing + fastest known for the QKV GEMM)
// ---------------------------------------------------------------------------
#define GQ_STAGE_A(bb, ca, kq) \
    async_copy16(pAc + (size_t)(ca) * 64 * K + (kq), \
                 &lds[(bb) * 28672 + (ca) * 4096 + stw]);

#define GQ_STAGE_B(bb, cb, kq) \
    async_copy16(pBc + (size_t)(cb) * 64 * K + (kq), \
                 &lds[(bb) * 28672 + 16384 + (cb) * 4096 + stw]);

#define GQ_LDA4(dst, bb, mi0) { \
    const int _b = (bb) * 28672 + wm * 8192; \
    _Pragma("unroll") \
    for (int mi = 0; mi < 4; mi++) { \
        const int _r = _b + (((mi0) + mi) * 16 + l16) * 64; \
        dst[mi * 2]     = *(const short8*)&lds[_r + col0]; \
        dst[mi * 2 + 1] = *(const short8*)&lds[_r + col1]; \
    } }

#define GQ_LDB2(dst, bb, ni0) { \
    const int _b = (bb) * 28672 + 16384 + wn * 3072; \
    _Pragma("unroll") \
    for (int ni = 0; ni < 2; ni++) { \
        const int _r = _b + (((ni0) + ni) * 16 + l16) * 64; \
        dst[ni * 2]     = *(const short8*)&lds[_r + col0]; \
        dst[ni * 2 + 1] = *(const short8*)&lds[_r + col1]; \
    } }

#define GQ_LDB1(dst, bb, ni0) { \
    const int _b = (bb) * 28672 + 16384 + wn * 3072; \
    const int _r = _b + ((ni0) * 16 + l16) * 64; \
    dst[0] = *(const short8*)&lds[_r + col0]; \
    dst[1] = *(const short8*)&lds[_r + col1]; }

// swapped operands: mfma(b, a) -> C col(l16)=m-row, row(quad*4+r)=n-col
#define GQ_MMA8(av, bv, MI0, NI0) { \
    _Pragma("unroll") \
    for (int mi = 0; mi < 4; mi++) \
    _Pragma("unroll") \
    for (int ni = 0; ni < 2; ni++) { \
        acc[(MI0) + mi][(NI0) + ni] = __builtin_amdgcn_mfma_f32_16x16x32_bf16( \
            bv[ni * 2],     av[mi * 2],     acc[(MI0) + mi][(NI0) + ni], 0, 0, 0); \
        acc[(MI0) + mi][(NI0) + ni] = __builtin_amdgcn_mfma_f32_16x16x32_bf16( \
            bv[ni * 2 + 1], av[mi * 2 + 1], acc[(MI0) + mi][(NI0) + ni], 0, 0, 0); \
    } }

#define GQ_MMA4(av, bv, MI0) { \
    _Pragma("unroll") \
    for (int mi = 0; mi < 4; mi++) { \
        acc[(MI0) + mi][2] = __builtin_amdgcn_mfma_f32_16x16x32_bf16( \
            bv[0], av[mi * 2],     acc[(MI0) + mi][2], 0, 0, 0); \
        acc[(MI0) + mi][2] = __builtin_amdgcn_mfma_f32_16x16x32_bf16( \
            bv[1], av[mi * 2 + 1], acc[(MI0) + mi][2], 0, 0, 0); \
    } }

template <typename OT>
__global__ __launch_bounds__(512, 2) void gemm_qkv(
    const u16* __restrict__ A, const u16* __restrict__ Bt,
    const float* __restrict__ bias, OT* __restrict__ C,
    int M, int N, int K)   // requires K >= 192 (NKT >= 3)
{
    __shared__ u16 lds[57344];   // 112 KiB = 2 buf x 7 chunks x 8 KB
    const int tid = threadIdx.x;
    const int w = tid >> 6, lane = tid & 63;
    const int l16 = lane & 15, quad = lane >> 4;
    const int wm = w >> 2, wn = w & 3;

    // XCD-aware swizzle (nwg % 8 == 0): contiguous tile chunk per XCD, x-fast
    const int nwgx = gridDim.x;
    const int nwg = nwgx * gridDim.y;
    const int lin = blockIdx.y * nwgx + blockIdx.x;
    const int cpx = nwg >> 3;
    const int swz = (lin & 7) * cpx + (lin >> 3);
    const int bn = (swz % nwgx) * 192, bm = (swz / nwgx) * 256;

    // staging: thread's 16B slot d in an 8 KB chunk; source = swz(d)
    const int d = tid * 16;
    const int s = d ^ (((d >> 7) & 7) << 4);
    const int r = s >> 7;              // row in chunk (0..63)
    const int c = (s & 127) >> 1;      // col element (0..63)
    const u16* pAc = A  + (size_t)(bm + r) * K + c;
    const u16* pBc = Bt + (size_t)(bn + r) * K + c;
    const int stw = w * 512;           // wave's slot base within a chunk (u16)

    // swizzled ds_read col offsets (u16), kc = 0 / 1
    const int xm = (l16 & 7) << 3;
    const int col0 = (quad * 8) ^ xm;
    const int col1 = (32 + quad * 8) ^ xm;

    floatx4 acc[8][3];
    #pragma unroll
    for (int i = 0; i < 8; i++)
        #pragma unroll
        for (int j = 0; j < 3; j++) acc[i][j] = (floatx4){0.f, 0.f, 0.f, 0.f};

    // prologue: A(0) c0-3, B(0) c0-2 -> buf0; B(1) c0-2 -> buf1. 10 issues;
    // vmcnt(3) = A(0)+B(0) landed (leaves B(1)); then pre-read a0,b0 of kt=0.
    GQ_STAGE_A(0, 0, 0); GQ_STAGE_A(0, 1, 0); GQ_STAGE_A(0, 2, 0); GQ_STAGE_A(0, 3, 0);
    GQ_STAGE_B(0, 0, 0); GQ_STAGE_B(0, 1, 0); GQ_STAGE_B(0, 2, 0);
    GQ_STAGE_B(1, 0, 64); GQ_STAGE_B(1, 1, 64); GQ_STAGE_B(1, 2, 64);
    asm volatile("s_waitcnt vmcnt(3)" ::: "memory");
    __syncthreads();

    short8 a0[8], a1[8], b0[4], b1[2];
    GQ_LDA4(a0, 0, 0);
    GQ_LDB2(b0, 0, 0);

    const int NKT = K >> 6;
    for (int kt = 0; kt < NKT; ++kt) {
        const int buf = kt & 1, nb = buf ^ 1;
        const int kqA = (kt + 1) << 6, kqB = (kt + 2) << 6;
        const bool st1 = (kt + 1 < NKT), st2 = (kt + 2 < NKT);

        // ---- ph0: read b1(kt); stage A c0,c1(kt+1); MMA Q00(a0,b0)
        GQ_LDB1(b1, buf, 2);
        if (st1) { GQ_STAGE_A(nb, 0, kqA); GQ_STAGE_A(nb, 1, kqA); }
        G256_BAR; G256_LGKM(2);
        __builtin_amdgcn_s_setprio(1); GQ_MMA8(a0, b0, 0, 0);
        __builtin_amdgcn_s_setprio(0); G256_BAR;

        // ---- ph1: read a1(kt); stage A c2,c3(kt+1); MMA Q01(a0,b1)
        GQ_LDA4(a1, buf, 4);
        if (st1) { GQ_STAGE_A(nb, 2, kqA); GQ_STAGE_A(nb, 3, kqA); }
        G256_BAR; G256_LGKM(8);
        __builtin_amdgcn_s_setprio(1); GQ_MMA4(a0, b1, 0);
        __builtin_amdgcn_s_setprio(0); G256_BAR;

        // ---- ph2: stage B c0,c1(kt+2); MMA Q10(a1,b0)
        if (st2) { GQ_STAGE_B(buf, 0, kqB); GQ_STAGE_B(buf, 1, kqB); }
        G256_BAR; G256_LGKM(0);
        __builtin_amdgcn_s_setprio(1); GQ_MMA8(a1, b0, 4, 0);
        __builtin_amdgcn_s_setprio(0); G256_BAR;

        // ---- ph3: stage B c2(kt+2); vmcnt; pre-read a0,b0(kt+1);
        //      MMA Q11(a1,b1) touches neither a0 nor b0 -> overlaps DS drain
        if (st2) { GQ_STAGE_B(buf, 2, kqB); }
        if (st1) {
            if (st2) { asm volatile("s_waitcnt vmcnt(3)" ::: "memory"); }
            else     { asm volatile("s_waitcnt vmcnt(0)" ::: "memory"); }
            __builtin_amdgcn_sched_barrier(0);
            GQ_LDA4(a0, nb, 0);
            GQ_LDB2(b0, nb, 0);
        }
        G256_BAR;
        __builtin_amdgcn_s_setprio(1); GQ_MMA4(a1, b1, 4);
        __builtin_amdgcn_s_setprio(0); G256_BAR;
    }

    // epilogue: lane holds 4 consecutive cols; mi-outer so each 64B line
    // is completed by back-to-back stores
    float4 bi[3];
    #pragma unroll
    for (int ni = 0; ni < 3; ni++)
        bi[ni] = *(const float4*)&bias[bn + wn * 48 + ni * 16 + quad * 4];
    #pragma unroll
    for (int mi = 0; mi < 8; mi++) {
        const int row = bm + wm * 128 + mi * 16 + l16;
        #pragma unroll
        for (int ni = 0; ni < 3; ni++) {
            const int col = bn + wn * 48 + ni * 16 + quad * 4;
            const float v0 = acc[mi][ni][0] + bi[ni].x;
            const float v1 = acc[mi][ni][1] + bi[ni].y;
            const float v2 = acc[mi][ni][2] + bi[ni].z;
            const float v3 = acc[mi][ni][3] + bi[ni].w;
            if constexpr (sizeof(OT) == 2) {
                u16 o[4] = {f2u(v0), f2u(v1), f2u(v2), f2u(v3)};
                *(short4v*)&((u16*)C)[(size_t)row * N + col] = *(short4v*)o;
            } else {
                float4 fv = {v0, v1, v2, v3};
                *(float4*)&C[(size_t)row * N + col] = fv;
            }
        }
    }
}

// ---------------------------------------------------------------------------
// gemm_out: 256x128 tile on the same 4-phase skeleton. Grid (N=1024):
// 8 x 32 = 256 blocks = exactly 1 dispatch round. 96 KiB LDS.
// (unchanged from round 7 — passing)
// ---------------------------------------------------------------------------
#define GO_STAGE_A(bb, ca, kq) \
    async_copy16(pAc + (size_t)(ca) * 64 * K + (kq), \
                 &lds[(bb) * 24576 + (ca) * 4096 + stw]);

#define GO_STAGE_B(bb, cb, kq) \
    async_copy16(pBc + (size_t)(cb) * 64 * K + (kq), \
                 &lds[(bb) * 24576 + 16384 + (cb) * 4096 + stw]);

#define GO_LDA4(dst, bb, mi0) { \
    const int _b = (bb) * 24576 + wm * 8192; \
    _Pragma("unroll") \
    for (int mi = 0; mi < 4; mi++) { \
        const int _r = _b + (((mi0) + mi) * 16 + l16) * 64; \
        dst[mi * 2]     = *(const short8*)&lds[_r + col0]; \
        dst[mi * 2 + 1] = *(const short8*)&lds[_r + col1]; \
    } }

#define GO_LDB1(dst, bb, ni) { \
    const int _b = (bb) * 24576 + 16384; \
    const int _r = _b + (wn * 32 + (ni) * 16 + l16) * 64; \
    dst[0] = *(const short8*)&lds[_r + col0]; \
    dst[1] = *(const short8*)&lds[_r + col1]; }

#define GO_MMA(av, bv, MI0, NI) { \
    _Pragma("unroll") \
    for (int mi = 0; mi < 4; mi++) { \
        acc[(MI0) + mi][NI] = __builtin_amdgcn_mfma_f32_16x16x32_bf16( \
            bv[0], av[mi * 2],     acc[(MI0) + mi][NI], 0, 0, 0); \
        acc[(MI0) + mi][NI] = __builtin_amdgcn_mfma_f32_16x16x32_bf16( \
            bv[1], av[mi * 2 + 1], acc[(MI0) + mi][NI], 0, 0, 0); \
    } }

__global__ __launch_bounds__(512, 2) void gemm_out(
    const u16* __restrict__ A, const u16* __restrict__ Bt,
    const float* __restrict__ bias, float* __restrict__ C,
    int M, int N, int K)   // requires K >= 192 (NKT >= 3)
{
    __shared__ u16 lds[49152];   // 96 KiB = 2 buf x 6 chunks x 8 KB
    const int tid = threadIdx.x;
    const int w = tid >> 6, lane = tid & 63;
    const int l16 = lane & 15, quad = lane >> 4;
    const int wm = w >> 2, wn = w & 3;

    // XCD-aware swizzle (nwg % 8 == 0)
    const int nwgx = gridDim.x;
    const int nwg = nwgx * gridDim.y;
    const int lin = blockIdx.y * nwgx + blockIdx.x;
    const int cpx = nwg >> 3;
    const int swz = (lin & 7) * cpx + (lin >> 3);
    const int bn = (swz % nwgx) * 128, bm = (swz / nwgx) * 256;

    // staging: thread's 16B slot d in an 8 KB chunk; source = swz(d)
    const int d = tid * 16;
    const int s = d ^ (((d >> 7) & 7) << 4);
    const int r = s >> 7;
    const int c = (s & 127) >> 1;
    const u16* pAc = A  + (size_t)(bm + r) * K + c;
    const u16* pBc = Bt + (size_t)(bn + r) * K + c;
    const int stw = w * 512;

    const int xm = (l16 & 7) << 3;
    const int col0 = (quad * 8) ^ xm;
    const int col1 = (32 + quad * 8) ^ xm;

    floatx4 acc[8][2];
    #pragma unroll
    for (int i = 0; i < 8; i++)
        #pragma unroll
        for (int j = 0; j < 2; j++) acc[i][j] = (floatx4){0.f, 0.f, 0.f, 0.f};

    // prologue: A(0) c0-3, B(0) c0-1 -> buf0; B(1) c0-1 -> buf1. 8 issues;
    // vmcnt(2) = A(0)+B(0) landed (leaves B(1)); pre-read a0,bb0 of kt=0.
    GO_STAGE_A(0, 0, 0); GO_STAGE_A(0, 1, 0); GO_STAGE_A(0, 2, 0); GO_STAGE_A(0, 3, 0);
    GO_STAGE_B(0, 0, 0); GO_STAGE_B(0, 1, 0);
    GO_STAGE_B(1, 0, 64); GO_STAGE_B(1, 1, 64);
    asm volatile("s_waitcnt vmcnt(2)" ::: "memory");
    __syncthreads();

    short8 a0[8], a1[8], bb0[2], bb1[2];
    GO_LDA4(a0, 0, 0);
    GO_LDB1(bb0, 0, 0);

    const int NKT = K >> 6;
    for (int kt = 0; kt < NKT; ++kt) {
        const int buf = kt & 1, nb = buf ^ 1;
        const int kqA = (kt + 1) << 6, kqB = (kt + 2) << 6;
        const bool st1 = (kt + 1 < NKT), st2 = (kt + 2 < NKT);

        // ---- ph0: read bb1(kt); stage A c0,c1(kt+1); MMA Q00(a0,bb0)
        GO_LDB1(bb1, buf, 1);
        if (st1) { GO_STAGE_A(nb, 0, kqA); GO_STAGE_A(nb, 1, kqA); }
        G256_BAR; G256_LGKM(2);
        __builtin_amdgcn_s_setprio(1); GO_MMA(a0, bb0, 0, 0);
        __builtin_amdgcn_s_setprio(0); G256_BAR;

        // ---- ph1: read a1(kt); stage A c2,c3(kt+1); MMA Q01(a0,bb1)
        GO_LDA4(a1, buf, 4);
        if (st1) { GO_STAGE_A(nb, 2, kqA); GO_STAGE_A(nb, 3, kqA); }
        G256_BAR; G256_LGKM(8);
        __builtin_amdgcn_s_setprio(1); GO_MMA(a0, bb1, 0, 1);
        __builtin_amdgcn_s_setprio(0); G256_BAR;

        // ---- ph2: stage B c0,c1(kt+2); MMA Q10(a1,bb0)
        if (st2) { GO_STAGE_B(buf, 0, kqB); GO_STAGE_B(buf, 1, kqB); }
        G256_BAR; G256_LGKM(0);
        __builtin_amdgcn_s_setprio(1); GO_MMA(a1, bb0, 4, 0);
        __builtin_amdgcn_s_setprio(0); G256_BAR;

        // ---- ph3: vmcnt; pre-read a0,bb0(kt+1); MMA Q11(a1,bb1)
        if (st1) {
            if (st2) { asm volatile("s_waitcnt vmcnt(2)" ::: "memory"); }
            else     { asm volatile("s_waitcnt vmcnt(0)" ::: "memory"); }
            __builtin_amdgcn_sched_barrier(0);
            GO_LDA4(a0, nb, 0);
            GO_LDB1(bb0, nb, 0);
        }
        G256_BAR;
        __builtin_amdgcn_s_setprio(1); GO_MMA(a1, bb1, 4, 1);
        __builtin_amdgcn_s_setprio(0); G256_BAR;
    }

    // epilogue: lane holds 4 consecutive cols (float4 stores)
    float4 bi[2];
    #pragma unroll
    for (int ni = 0; ni < 2; ni++)
        bi[ni] = *(const float4*)&bias[bn + wn * 32 + ni * 16 + quad * 4];
    #pragma unroll
    for (int mi = 0; mi < 8; mi++) {
        const int row = bm + wm * 128 + mi * 16 + l16;
        #pragma unroll
        for (int ni = 0; ni < 2; ni++) {
            const int col = bn + wn * 32 + ni * 16 + quad * 4;
            float4 fv = {acc[mi][ni][0] + bi[ni].x, acc[mi][ni][1] + bi[ni].y,
                         acc[mi][ni][2] + bi[ni].z, acc[mi][ni][3] + bi[ni].w};
            *(float4*)&C[(size_t)row * N + col] = fv;
        }
    }
}

// ---------------------------------------------------------------------------
// attn_mfma v6: v5 structure (40 KiB LDS, per-wave Ps slice) but NO
// register cap — round-7's __launch_bounds__(256,4) clamped the allocator
// to 64 VGPRs and spilled ~565 KB/block to scratch (WRITE_SIZE 16->578 MB,
// 3.3x slowdown). Plain (256) lets the allocator use ~110-120 VGPRs like
// the passing v4; LDS=40KB still admits 4 blocks/CU if VGPR <= 128.
// ---------------------------------------------------------------------------
__global__ __launch_bounds__(256) void attn_mfma(
    const u16* __restrict__ QKV, const u16* __restrict__ Vtg, u16* __restrict__ ctx)
{
    __shared__ u16 Ks[2][64 * 64];   // [key][d], chunk-swizzled   16 KB
    __shared__ u16 Vs[2][64 * 64];   // [d][key], chunk-swizzled   16 KB
    __shared__ u16 Ps[4 * 16 * 64];  // per-wave 16-row P slice     8 KB

    const int bh = blockIdx.x;
    const int qt = (int)(gridDim.y - 1) - (int)blockIdx.y;   // long blocks first
    const int b = bh >> 4, h = bh & 15;
    const int tid = threadIdx.x;
    const int w = tid >> 6, lane = tid & 63;
    const int l16 = lane & 15, quad = lane >> 4;

    // staging geometry: 512 chunks of 16B per 8KB tile; thread handles f, f+256
    const int r0 = tid >> 3,        c0 = tid & 7;          // f = tid
    const int r1 = (256 + tid) >> 3, c1 = tid & 7;         // f = 256+tid
    const int sw0 = c0 ^ (r0 & 7), sw1 = c1 ^ (r1 & 7);

    // Q fragments (MFMA B-operand): lane l16 <-> q-row, k = quad*8+j
    short8 q[2][2];
    #pragma unroll
    for (int m = 0; m < 2; m++) {
        const u16* qp = QKV + (size_t)(b * SEQ + qt * 128 + w * 32 + m * 16 + l16) * N_QKV + h * 64;
        q[m][0] = *(const short8*)&qp[quad * 8];
        q[m][1] = *(const short8*)&qp[32 + quad * 8];
    }

    // ones fragment for MFMA row-sum (bf16 1.0 = 0x3F80)
    short8 ones8;
    #pragma unroll
    for (int i = 0; i < 8; i++) ones8[i] = (short)0x3F80;

    floatx4 O[2][4];               // O^T: rows d, col qrow=l16
    floatx4 lsum[2];               // row-sum accumulator (all regs = sum)
    #pragma unroll
    for (int m = 0; m < 2; m++) {
        lsum[m] = (floatx4){0.f, 0.f, 0.f, 0.f};
        #pragma unroll
        for (int i = 0; i < 4; i++) O[m][i] = (floatx4){0.f, 0.f, 0.f, 0.f};
    }

    const int nkt = 2 * qt + 2;
    const int qrow_w_max = qt * 128 + w * 32 + 31;

    const size_t kbase = (size_t)(b * SEQ) * N_QKV + D_MODEL + h * 64;
    const size_t vbase = (size_t)bh * 64 * SEQ;

    // running prefetch pointers (advance by one K-tile per iteration)
    const u16* kpa = QKV + kbase + (size_t)r0 * N_QKV + c0 * 8;
    const u16* kpb = QKV + kbase + (size_t)r1 * N_QKV + c1 * 8;
    const u16* vpa = Vtg + vbase + (size_t)r0 * SEQ + c0 * 8;
    const u16* vpb = Vtg + vbase + (size_t)r1 * SEQ + c1 * 8;

    // prologue: tile 0 -> buf 0
    {
        float4 ka = *(const float4*)kpa;
        float4 kb = *(const float4*)kpb;
        float4 va = *(const float4*)vpa;
        float4 vb = *(const float4*)vpb;
        *(float4*)&Ks[0][r0 * 64 + sw0 * 8] = ka;
        *(float4*)&Ks[0][r1 * 64 + sw1 * 8] = kb;
        *(float4*)&Vs[0][r0 * 64 + sw0 * 8] = va;
        *(float4*)&Vs[0][r1 * 64 + sw1 * 8] = vb;
    }
    kpa += (size_t)64 * N_QKV; kpb += (size_t)64 * N_QKV;
    vpa += 64; vpb += 64;
    __syncthreads();

    const int e7 = l16 & 7;
    const int pbase = w * 1024 + l16 * 64;   // wave slice, row = l16

    for (int kt = 0; kt < nkt; kt++) {
        const int buf = kt & 1;
        const bool pre = (kt + 1 < nkt);
        float4 ka, kb, va, vb;
        if (pre) {
            ka = *(const float4*)kpa;
            kb = *(const float4*)kpb;
            va = *(const float4*)vpa;
            vb = *(const float4*)vpb;
            kpa += (size_t)64 * N_QKV; kpb += (size_t)64 * N_QKV;
            vpa += 64; vpb += 64;
        }

        if (kt * 64 <= qrow_w_max) {
            // K fragments, swizzle-decoded
            short8 kf[4][2];
            #pragma unroll
            for (int ns = 0; ns < 4; ns++) {
                const int rr = ns * 16 + l16, rs = rr & 7;
                kf[ns][0] = *(short8*)&Ks[buf][rr * 64 + (quad ^ rs) * 8];
                kf[ns][1] = *(short8*)&Ks[buf][rr * 64 + ((4 + quad) ^ rs) * 8];
            }
            const bool needMask = (kt * 64 + 63 > qt * 128 + w * 32);

            // QK^T for both m (z in regs; kf dead afterwards)
            floatx4 z[2][4];
            __builtin_amdgcn_s_setprio(1);
            #pragma unroll
            for (int m = 0; m < 2; m++)
                #pragma unroll
                for (int ns = 0; ns < 4; ns++) {
                    floatx4 t = (floatx4){0.f, 0.f, 0.f, 0.f};
                    t = __builtin_amdgcn_mfma_f32_16x16x32_bf16(kf[ns][0], q[m][0], t, 0, 0, 0);
                    t = __builtin_amdgcn_mfma_f32_16x16x32_bf16(kf[ns][1], q[m][1], t, 0, 0, 0);
                    z[m][ns] = t;
                }
            __builtin_amdgcn_s_setprio(0);

            // V fragments
            short8 vf[4][2];
            #pragma unroll
            for (int ds = 0; ds < 4; ds++) {
                const int rr = ds * 16 + l16, rs = rr & 7;
                vf[ds][0] = *(short8*)&Vs[buf][rr * 64 + (quad ^ rs) * 8];
                vf[ds][1] = *(short8*)&Vs[buf][rr * 64 + ((4 + quad) ^ rs) * 8];
            }

            // per-m: softmax -> slice write -> p read -> lsum + PV
            #pragma unroll
            for (int m = 0; m < 2; m++) {
                const int qrow_g = qt * 128 + w * 32 + m * 16 + l16;
                #pragma unroll
                for (int ns = 0; ns < 4; ns++) {
                    u16 pk[4];
                    #pragma unroll
                    for (int r = 0; r < 4; r++) {
                        float s = z[m][ns][r];
                        const int key = kt * 64 + ns * 16 + quad * 4 + r;
                        if (needMask && key > qrow_g) s = -INFINITY;
                        float p = __builtin_amdgcn_exp2f(s - EXP2_OFF);
                        pk[r] = f2u(p);
                    }
                    // 8B block (ns*4+quad) XOR-swizzled by 2*e7
                    *(short4v*)&Ps[pbase + (((ns * 4 + quad) ^ (2 * e7)) << 2)] = *(short4v*)pk;
                }
                short8 p0 = *(short8*)&Ps[pbase + ((quad ^ e7) << 3)];
                short8 p1 = *(short8*)&Ps[pbase + (((4 + quad) ^ e7) << 3)];
                __builtin_amdgcn_s_setprio(1);
                lsum[m] = __builtin_amdgcn_mfma_f32_16x16x32_bf16(ones8, p0, lsum[m], 0, 0, 0);
                lsum[m] = __builtin_amdgcn_mfma_f32_16x16x32_bf16(ones8, p1, lsum[m], 0, 0, 0);
                #pragma unroll
                for (int ds = 0; ds < 4; ds++) {
                    O[m][ds] = __builtin_amdgcn_mfma_f32_16x16x32_bf16(vf[ds][0], p0, O[m][ds], 0, 0, 0);
                    O[m][ds] = __builtin_amdgcn_mfma_f32_16x16x32_bf16(vf[ds][1], p1, O[m][ds], 0, 0, 0);
                }
                __builtin_amdgcn_s_setprio(0);
            }
        }

        if (pre) {
            const int nb = buf ^ 1;
            *(float4*)&Ks[nb][r0 * 64 + sw0 * 8] = ka;
            *(float4*)&Ks[nb][r1 * 64 + sw1 * 8] = kb;
            *(float4*)&Vs[nb][r0 * 64 + sw0 * 8] = va;
            *(float4*)&Vs[nb][r1 * 64 + sw1 * 8] = vb;
        }
        __syncthreads();
    }

    // epilogue: O^T / l -> ctx[qrow][d], packed 8 B stores
    #pragma unroll
    for (int m = 0; m < 2; m++) {
        const float inv = 1.0f / lsum[m][0];
        const size_t base = (size_t)(b * SEQ + qt * 128 + w * 32 + m * 16 + l16) * D_MODEL + h * 64;
        #pragma unroll
        for (int ds = 0; ds < 4; ds++) {
            u16 o[4];
            #pragma unroll
            for (int r = 0; r < 4; r++) o[r] = f2u(O[m][ds][r] * inv);
            *(short4v*)&ctx[base + ds * 16 + quad * 4] = *(short4v*)o;
        }
    }
}

// ---------------------------------------------------------------------------
extern "C" void kernel_launch(void* const* d_in, const int* in_sizes, int n_in,
                              void* d_out, int out_size, void* d_ws, size_t ws_size,
                              hipStream_t stream) {
    const float* x  = (const float*)d_in[0];
    const float* Wq = (const float*)d_in[1];
    const float* bq = (const float*)d_in[2];
    const float* Wk = (const float*)d_in[3];
    const float* bk = (const float*)d_in[4];
    const float* Wv = (const float*)d_in[5];
    const float* bv = (const float*)d_in[6];
    const float* Wo = (const float*)d_in[7];
    const float* bo = (const float*)d_in[8];
    float* out = (float*)d_out;

    // workspace (bytes): total 0x5840000 = 92.3 MB (Vtg overlays dead xb)
    char* ws = (char*)d_ws;
    float* biasp = (float*)ws;                       // 16 KB
    u16*   Wpt   = (u16*)(ws + 0x10000);             // 6 MB  [3072][1024]
    u16*   Wot   = (u16*)(ws + 0x620000);            // 2 MB  [1024][1024]
    u16*   xb    = (u16*)(ws + 0x840000);            // 16 MB [8192][1024]
    u16*   Vtg   = xb;                               // overlay: xb dead after QKV GEMM
    u16*   QKV   = (u16*)(ws + 0x1840000);           // 48 MB [8192][3072]
    u16*   ctx   = (u16*)(ws + 0x4840000);           // 16 MB [8192][1024]

    prep<<<5121, 256, 0, stream>>>(x, Wq, Wk, Wv, Wo, bq, bk, bv, bo,
                                   xb, Wpt, Wot, biasp);

    gemm_qkv<u16><<<dim3(N_QKV / 192, M_ROWS / 256), 512, 0, stream>>>(
        xb, Wpt, biasp, QKV, M_ROWS, N_QKV, D_MODEL);

    vtrans<<<dim3(64, 32), 256, 0, stream>>>(QKV, Vtg);

    attn_mfma<<<dim3(BATCH * NH, SEQ / 128), 256, 0, stream>>>(QKV, Vtg, ctx);

    gemm_out<<<dim3(D_MODEL / 128, M_ROWS / 256), 512, 0, stream>>>(
        ctx, Wot, biasp + N_QKV, out, M_ROWS, D_MODEL, D_MODEL);
}

// Round 9
// 256.700 us; speedup vs baseline: 1.7377x; 1.0820x over previous
//
#include <hip/hip_runtime.h>
#include <hip/hip_bf16.h>

typedef unsigned short u16;
typedef __attribute__((ext_vector_type(8))) short short8;   // 8 bf16 = 4 VGPRs
typedef __attribute__((ext_vector_type(4))) short short4v;  // 4 bf16 = 8 B
typedef __attribute__((ext_vector_type(4))) float floatx4;  // MFMA C/D

#define D_MODEL 1024
#define NH 16
#define SEQ 2048
#define BATCH 4
#define M_ROWS 8192
#define N_QKV 3072
#define N_QK 2048   // QK buffer row stride (Q cols 0..1023, K cols 1024..2047)
#define PS_LD 72    // Ps row stride (u16): 144 B = 16B-aligned, 4-bank rotate/row

// Q-path prescale: 1/sqrt(64) * log2(e) so softmax is exp2(s - 8*log2e)
#define QSCALE 0.18033688011112042f
#define EXP2_OFF 11.541560327111707f   // 8 * log2(e)

__device__ __forceinline__ u16 f2u(float f) {
    __hip_bfloat16 h = __float2bfloat16(f);
    u16 u; __builtin_memcpy(&u, &h, 2); return u;
}

// async global->LDS, 16B per lane; dest = wave-uniform base + lane*16
__device__ __forceinline__ void async_copy16(const u16* g, u16* l) {
    __builtin_amdgcn_global_load_lds(
        (const __attribute__((address_space(1))) unsigned int*)(g),
        (__attribute__((address_space(3))) unsigned int*)(l),
        16, 0, 0);
}

// ---------------------------------------------------------------------------
// prep (one launch): blocks 0..4095 convert x->bf16; 4096..5119 transpose
// weights (Wq pre-scaled by QSCALE); block 5120 packs biases.
// ---------------------------------------------------------------------------
__global__ __launch_bounds__(256) void prep(
    const float* __restrict__ x,
    const float* __restrict__ Wq, const float* __restrict__ Wk,
    const float* __restrict__ Wv, const float* __restrict__ Wo,
    const float* __restrict__ bq, const float* __restrict__ bk,
    const float* __restrict__ bv, const float* __restrict__ bo,
    u16* __restrict__ xb, u16* __restrict__ Wpt, u16* __restrict__ Wot,
    float* __restrict__ biasp)
{
    __shared__ u16 T[64 * 72];
    const int tid = threadIdx.x;
    const int blk = blockIdx.x;

    if (blk < 4096) {                       // x -> bf16
        size_t i = ((size_t)blk * 256 + tid) * 8;
        float4 f0 = *(const float4*)&x[i];
        float4 f1 = *(const float4*)&x[i + 4];
        u16 t[8] = {f2u(f0.x), f2u(f0.y), f2u(f0.z), f2u(f0.w),
                    f2u(f1.x), f2u(f1.y), f2u(f1.z), f2u(f1.w)};
        *(short8*)&xb[i] = *(short8*)t;
        return;
    }
    if (blk == 5120) {                      // biases
        #pragma unroll
        for (int j = 0; j < 16; j++) {
            int idx = j * 256 + tid;
            float v;
            if (idx < 1024)      v = bq[idx] * QSCALE;
            else if (idx < 2048) v = bk[idx - 1024];
            else if (idx < 3072) v = bv[idx - 2048];
            else                 v = bo[idx - 3072];
            biasp[idx] = v;
        }
        return;
    }
    const int wb = blk - 4096;              // 0..1023: weight transpose
    const int r = tid >> 2, s4 = (tid & 3) * 16;
    if (wb < 768) {
        int sel = wb / 256, rem = wb % 256;
        int h = rem >> 4, ktile = rem & 15;
        const float* W = (sel == 0) ? Wq : ((sel == 1) ? Wk : Wv);
        const float scale = (sel == 0) ? QSCALE : 1.0f;
        const float* src = W + ((size_t)h * 1024 + ktile * 64 + r) * 64 + s4;
        #pragma unroll
        for (int i = 0; i < 16; i++) T[(s4 + i) * 72 + r] = f2u(src[i] * scale);
        __syncthreads();
        u16 tmp[16];
        #pragma unroll
        for (int i = 0; i < 16; i++) tmp[i] = T[r * 72 + s4 + i];
        u16* dst = Wpt + ((size_t)sel * 1024 + h * 64 + r) * 1024 + ktile * 64 + s4;
        *(short8*)&dst[0] = *(short8*)&tmp[0];
        *(short8*)&dst[8] = *(short8*)&tmp[8];
    } else {
        int rem = wb - 768;
        int nt = rem >> 4, kt2 = rem & 15;
        const float* src = Wo + ((size_t)kt2 * 64 + r) * 1024 + nt * 64 + s4;
        #pragma unroll
        for (int i = 0; i < 16; i++) T[(s4 + i) * 72 + r] = f2u(src[i]);
        __syncthreads();
        u16 tmp[16];
        #pragma unroll
        for (int i = 0; i < 16; i++) tmp[i] = T[r * 72 + s4 + i];
        u16* dst = Wot + ((size_t)nt * 64 + r) * 1024 + kt2 * 64 + s4;
        *(short8*)&dst[0] = *(short8*)&tmp[0];
        *(short8*)&dst[8] = *(short8*)&tmp[8];
    }
}

// ---------------------------------------------------------------------------
// Shared macros for the 4-phase 8-wave GEMM skeleton (r5-proven).
// ---------------------------------------------------------------------------
#define G256_BAR   __builtin_amdgcn_s_barrier()
#define G256_LGKM(n) { asm volatile("s_waitcnt lgkmcnt(" #n ")" ::: "memory"); \
                       __builtin_amdgcn_sched_barrier(0); }

// ---------------------------------------------------------------------------
// gemm_qkv: 256x192 tile (tail-free: 16x32 = 512 blocks = exactly 2 rounds),
// BK=64, 8 waves (2M x 4N), 112 KiB LDS, 4-phase read-one-phase-ahead.
// FUSED V-TRANSPOSE EPILOGUE: cols < 2048 (Q,K) -> QK[row][col] packed 8B;
// cols >= 2048 (V) -> Vtg[bh][d][key] directly (4 scalar u16 stores/lane;
// per wave-store: 4 d-rows x 32B segments). Branch is wave-uniform (colbase
// lane-independent, 2048 boundary 16-aligned, d0+3 <= 63 so no h-crossing).
// Replaces the former vtrans kernel (saves its compute + one launch).
// ---------------------------------------------------------------------------
#define GQ_STAGE_A(bb, ca, kq) \
    async_copy16(pAc + (size_t)(ca) * 64 * K + (kq), \
                 &lds[(bb) * 28672 + (ca) * 4096 + stw]);

#define GQ_STAGE_B(bb, cb, kq) \
    async_copy16(pBc + (size_t)(cb) * 64 * K + (kq), \
                 &lds[(bb) * 28672 + 16384 + (cb) * 4096 + stw]);

#define GQ_LDA4(dst, bb, mi0) { \
    const int _b = (bb) * 28672 + wm * 8192; \
    _Pragma("unroll") \
    for (int mi = 0; mi < 4; mi++) { \
        const int _r = _b + (((mi0) + mi) * 16 + l16) * 64; \
        dst[mi * 2]     = *(const short8*)&lds[_r + col0]; \
        dst[mi * 2 + 1] = *(const short8*)&lds[_r + col1]; \
    } }

#define GQ_LDB2(dst, bb, ni0) { \
    const int _b = (bb) * 28672 + 16384 + wn * 3072; \
    _Pragma("unroll") \
    for (int ni = 0; ni < 2; ni++) { \
        const int _r = _b + (((ni0) + ni) * 16 + l16) * 64; \
        dst[ni * 2]     = *(const short8*)&lds[_r + col0]; \
        dst[ni * 2 + 1] = *(const short8*)&lds[_r + col1]; \
    } }

#define GQ_LDB1(dst, bb, ni0) { \
    const int _b = (bb) * 28672 + 16384 + wn * 3072; \
    const int _r = _b + ((ni0) * 16 + l16) * 64; \
    dst[0] = *(const short8*)&lds[_r + col0]; \
    dst[1] = *(const short8*)&lds[_r + col1]; }

// swapped operands: mfma(b, a) -> C col(l16)=m-row, row(quad*4+r)=n-col
#define GQ_MMA8(av, bv, MI0, NI0) { \
    _Pragma("unroll") \
    for (int mi = 0; mi < 4; mi++) \
    _Pragma("unroll") \
    for (int ni = 0; ni < 2; ni++) { \
        acc[(MI0) + mi][(NI0) + ni] = __builtin_amdgcn_mfma_f32_16x16x32_bf16( \
            bv[ni * 2],     av[mi * 2],     acc[(MI0) + mi][(NI0) + ni], 0, 0, 0); \
        acc[(MI0) + mi][(NI0) + ni] = __builtin_amdgcn_mfma_f32_16x16x32_bf16( \
            bv[ni * 2 + 1], av[mi * 2 + 1], acc[(MI0) + mi][(NI0) + ni], 0, 0, 0); \
    } }

#define GQ_MMA4(av, bv, MI0) { \
    _Pragma("unroll") \
    for (int mi = 0; mi < 4; mi++) { \
        acc[(MI0) + mi][2] = __builtin_amdgcn_mfma_f32_16x16x32_bf16( \
            bv[0], av[mi * 2],     acc[(MI0) + mi][2], 0, 0, 0); \
        acc[(MI0) + mi][2] = __builtin_amdgcn_mfma_f32_16x16x32_bf16( \
            bv[1], av[mi * 2 + 1], acc[(MI0) + mi][2], 0, 0, 0); \
    } }

__global__ __launch_bounds__(512, 2) void gemm_qkv(
    const u16* __restrict__ A, const u16* __restrict__ Bt,
    const float* __restrict__ bias, u16* __restrict__ C,
    u16* __restrict__ Vtg, int M, int N, int K)
{
    __shared__ u16 lds[57344];   // 112 KiB = 2 buf x 7 chunks x 8 KB
    const int tid = threadIdx.x;
    const int w = tid >> 6, lane = tid & 63;
    const int l16 = lane & 15, quad = lane >> 4;
    const int wm = w >> 2, wn = w & 3;

    // XCD-aware swizzle (nwg % 8 == 0): contiguous tile chunk per XCD, x-fast
    const int nwgx = gridDim.x;
    const int nwg = nwgx * gridDim.y;
    const int lin = blockIdx.y * nwgx + blockIdx.x;
    const int cpx = nwg >> 3;
    const int swz = (lin & 7) * cpx + (lin >> 3);
    const int bn = (swz % nwgx) * 192, bm = (swz / nwgx) * 256;

    // staging: thread's 16B slot d in an 8 KB chunk; source = swz(d)
    const int d = tid * 16;
    const int s = d ^ (((d >> 7) & 7) << 4);
    const int r = s >> 7;              // row in chunk (0..63)
    const int c = (s & 127) >> 1;      // col element (0..63)
    const u16* pAc = A  + (size_t)(bm + r) * K + c;
    const u16* pBc = Bt + (size_t)(bn + r) * K + c;
    const int stw = w * 512;           // wave's slot base within a chunk (u16)

    // swizzled ds_read col offsets (u16), kc = 0 / 1
    const int xm = (l16 & 7) << 3;
    const int col0 = (quad * 8) ^ xm;
    const int col1 = (32 + quad * 8) ^ xm;

    floatx4 acc[8][3];
    #pragma unroll
    for (int i = 0; i < 8; i++)
        #pragma unroll
        for (int j = 0; j < 3; j++) acc[i][j] = (floatx4){0.f, 0.f, 0.f, 0.f};

    // prologue: A(0) c0-3, B(0) c0-2 -> buf0; B(1) c0-2 -> buf1. 10 issues;
    // vmcnt(3) = A(0)+B(0) landed (leaves B(1)); then pre-read a0,b0 of kt=0.
    GQ_STAGE_A(0, 0, 0); GQ_STAGE_A(0, 1, 0); GQ_STAGE_A(0, 2, 0); GQ_STAGE_A(0, 3, 0);
    GQ_STAGE_B(0, 0, 0); GQ_STAGE_B(0, 1, 0); GQ_STAGE_B(0, 2, 0);
    GQ_STAGE_B(1, 0, 64); GQ_STAGE_B(1, 1, 64); GQ_STAGE_B(1, 2, 64);
    asm volatile("s_waitcnt vmcnt(3)" ::: "memory");
    __syncthreads();

    short8 a0[8], a1[8], b0[4], b1[2];
    GQ_LDA4(a0, 0, 0);
    GQ_LDB2(b0, 0, 0);

    const int NKT = K >> 6;
    for (int kt = 0; kt < NKT; ++kt) {
        const int buf = kt & 1, nb = buf ^ 1;
        const int kqA = (kt + 1) << 6, kqB = (kt + 2) << 6;
        const bool st1 = (kt + 1 < NKT), st2 = (kt + 2 < NKT);

        // ---- ph0: read b1(kt); stage A c0,c1(kt+1); MMA Q00(a0,b0)
        GQ_LDB1(b1, buf, 2);
        if (st1) { GQ_STAGE_A(nb, 0, kqA); GQ_STAGE_A(nb, 1, kqA); }
        G256_BAR; G256_LGKM(2);
        __builtin_amdgcn_s_setprio(1); GQ_MMA8(a0, b0, 0, 0);
        __builtin_amdgcn_s_setprio(0); G256_BAR;

        // ---- ph1: read a1(kt); stage A c2,c3(kt+1); MMA Q01(a0,b1)
        GQ_LDA4(a1, buf, 4);
        if (st1) { GQ_STAGE_A(nb, 2, kqA); GQ_STAGE_A(nb, 3, kqA); }
        G256_BAR; G256_LGKM(8);
        __builtin_amdgcn_s_setprio(1); GQ_MMA4(a0, b1, 0);
        __builtin_amdgcn_s_setprio(0); G256_BAR;

        // ---- ph2: stage B c0,c1(kt+2); MMA Q10(a1,b0)
        if (st2) { GQ_STAGE_B(buf, 0, kqB); GQ_STAGE_B(buf, 1, kqB); }
        G256_BAR; G256_LGKM(0);
        __builtin_amdgcn_s_setprio(1); GQ_MMA8(a1, b0, 4, 0);
        __builtin_amdgcn_s_setprio(0); G256_BAR;

        // ---- ph3: stage B c2(kt+2); vmcnt; pre-read a0,b0(kt+1);
        //      MMA Q11(a1,b1) touches neither a0 nor b0 -> overlaps DS drain
        if (st2) { GQ_STAGE_B(buf, 2, kqB); }
        if (st1) {
            if (st2) { asm volatile("s_waitcnt vmcnt(3)" ::: "memory"); }
            else     { asm volatile("s_waitcnt vmcnt(0)" ::: "memory"); }
            __builtin_amdgcn_sched_barrier(0);
            GQ_LDA4(a0, nb, 0);
            GQ_LDB2(b0, nb, 0);
        }
        G256_BAR;
        __builtin_amdgcn_s_setprio(1); GQ_MMA4(a1, b1, 4);
        __builtin_amdgcn_s_setprio(0); G256_BAR;
    }

    // epilogue: lane holds 4 consecutive cols. Q/K -> QK packed 8B stores;
    // V -> Vtg[bh][d][key] transposed (fused vtrans).
    float4 bi[3];
    #pragma unroll
    for (int ni = 0; ni < 3; ni++)
        bi[ni] = *(const float4*)&bias[bn + wn * 48 + ni * 16 + quad * 4];
    #pragma unroll
    for (int mi = 0; mi < 8; mi++) {
        const int row = bm + wm * 128 + mi * 16 + l16;
        #pragma unroll
        for (int ni = 0; ni < 3; ni++) {
            const int colbase = bn + wn * 48 + ni * 16;   // wave-uniform
            const int col = colbase + quad * 4;
            const float v0 = acc[mi][ni][0] + bi[ni].x;
            const float v1 = acc[mi][ni][1] + bi[ni].y;
            const float v2 = acc[mi][ni][2] + bi[ni].z;
            const float v3 = acc[mi][ni][3] + bi[ni].w;
            if (colbase < 2048) {
                u16 o[4] = {f2u(v0), f2u(v1), f2u(v2), f2u(v3)};
                *(short4v*)&C[(size_t)row * N_QK + col] = *(short4v*)o;
            } else {
                const int dh = col - 2048;                 // 64*h + d0
                const size_t vrow =
                    ((size_t)((row >> 11) * 16 + (dh >> 6)) * 64 + (dh & 63)) * SEQ
                    + (row & 2047);
                Vtg[vrow]            = f2u(v0);
                Vtg[vrow + SEQ]      = f2u(v1);
                Vtg[vrow + 2 * SEQ]  = f2u(v2);
                Vtg[vrow + 3 * SEQ]  = f2u(v3);
            }
        }
    }
}

// ---------------------------------------------------------------------------
// gemm_out: 256x128 tile on the same 4-phase skeleton. Grid (N=1024):
// 8 x 32 = 256 blocks = exactly 1 dispatch round. 96 KiB LDS. (unchanged)
// ---------------------------------------------------------------------------
#define GO_STAGE_A(bb, ca, kq) \
    async_copy16(pAc + (size_t)(ca) * 64 * K + (kq), \
                 &lds[(bb) * 24576 + (ca) * 4096 + stw]);

#define GO_STAGE_B(bb, cb, kq) \
    async_copy16(pBc + (size_t)(cb) * 64 * K + (kq), \
                 &lds[(bb) * 24576 + 16384 + (cb) * 4096 + stw]);

#define GO_LDA4(dst, bb, mi0) { \
    const int _b = (bb) * 24576 + wm * 8192; \
    _Pragma("unroll") \
    for (int mi = 0; mi < 4; mi++) { \
        const int _r = _b + (((mi0) + mi) * 16 + l16) * 64; \
        dst[mi * 2]     = *(const short8*)&lds[_r + col0]; \
        dst[mi * 2 + 1] = *(const short8*)&lds[_r + col1]; \
    } }

#define GO_LDB1(dst, bb, ni) { \
    const int _b = (bb) * 24576 + 16384; \
    const int _r = _b + (wn * 32 + (ni) * 16 + l16) * 64; \
    dst[0] = *(const short8*)&lds[_r + col0]; \
    dst[1] = *(const short8*)&lds[_r + col1]; }

#define GO_MMA(av, bv, MI0, NI) { \
    _Pragma("unroll") \
    for (int mi = 0; mi < 4; mi++) { \
        acc[(MI0) + mi][NI] = __builtin_amdgcn_mfma_f32_16x16x32_bf16( \
            bv[0], av[mi * 2],     acc[(MI0) + mi][NI], 0, 0, 0); \
        acc[(MI0) + mi][NI] = __builtin_amdgcn_mfma_f32_16x16x32_bf16( \
            bv[1], av[mi * 2 + 1], acc[(MI0) + mi][NI], 0, 0, 0); \
    } }

__global__ __launch_bounds__(512, 2) void gemm_out(
    const u16* __restrict__ A, const u16* __restrict__ Bt,
    const float* __restrict__ bias, float* __restrict__ C,
    int M, int N, int K)   // requires K >= 192 (NKT >= 3)
{
    __shared__ u16 lds[49152];   // 96 KiB = 2 buf x 6 chunks x 8 KB
    const int tid = threadIdx.x;
    const int w = tid >> 6, lane = tid & 63;
    const int l16 = lane & 15, quad = lane >> 4;
    const int wm = w >> 2, wn = w & 3;

    // XCD-aware swizzle (nwg % 8 == 0)
    const int nwgx = gridDim.x;
    const int nwg = nwgx * gridDim.y;
    const int lin = blockIdx.y * nwgx + blockIdx.x;
    const int cpx = nwg >> 3;
    const int swz = (lin & 7) * cpx + (lin >> 3);
    const int bn = (swz % nwgx) * 128, bm = (swz / nwgx) * 256;

    // staging: thread's 16B slot d in an 8 KB chunk; source = swz(d)
    const int d = tid * 16;
    const int s = d ^ (((d >> 7) & 7) << 4);
    const int r = s >> 7;
    const int c = (s & 127) >> 1;
    const u16* pAc = A  + (size_t)(bm + r) * K + c;
    const u16* pBc = Bt + (size_t)(bn + r) * K + c;
    const int stw = w * 512;

    const int xm = (l16 & 7) << 3;
    const int col0 = (quad * 8) ^ xm;
    const int col1 = (32 + quad * 8) ^ xm;

    floatx4 acc[8][2];
    #pragma unroll
    for (int i = 0; i < 8; i++)
        #pragma unroll
        for (int j = 0; j < 2; j++) acc[i][j] = (floatx4){0.f, 0.f, 0.f, 0.f};

    // prologue: A(0) c0-3, B(0) c0-1 -> buf0; B(1) c0-1 -> buf1. 8 issues;
    // vmcnt(2) = A(0)+B(0) landed (leaves B(1)); pre-read a0,bb0 of kt=0.
    GO_STAGE_A(0, 0, 0); GO_STAGE_A(0, 1, 0); GO_STAGE_A(0, 2, 0); GO_STAGE_A(0, 3, 0);
    GO_STAGE_B(0, 0, 0); GO_STAGE_B(0, 1, 0);
    GO_STAGE_B(1, 0, 64); GO_STAGE_B(1, 1, 64);
    asm volatile("s_waitcnt vmcnt(2)" ::: "memory");
    __syncthreads();

    short8 a0[8], a1[8], bb0[2], bb1[2];
    GO_LDA4(a0, 0, 0);
    GO_LDB1(bb0, 0, 0);

    const int NKT = K >> 6;
    for (int kt = 0; kt < NKT; ++kt) {
        const int buf = kt & 1, nb = buf ^ 1;
        const int kqA = (kt + 1) << 6, kqB = (kt + 2) << 6;
        const bool st1 = (kt + 1 < NKT), st2 = (kt + 2 < NKT);

        // ---- ph0: read bb1(kt); stage A c0,c1(kt+1); MMA Q00(a0,bb0)
        GO_LDB1(bb1, buf, 1);
        if (st1) { GO_STAGE_A(nb, 0, kqA); GO_STAGE_A(nb, 1, kqA); }
        G256_BAR; G256_LGKM(2);
        __builtin_amdgcn_s_setprio(1); GO_MMA(a0, bb0, 0, 0);
        __builtin_amdgcn_s_setprio(0); G256_BAR;

        // ---- ph1: read a1(kt); stage A c2,c3(kt+1); MMA Q01(a0,bb1)
        GO_LDA4(a1, buf, 4);
        if (st1) { GO_STAGE_A(nb, 2, kqA); GO_STAGE_A(nb, 3, kqA); }
        G256_BAR; G256_LGKM(8);
        __builtin_amdgcn_s_setprio(1); GO_MMA(a0, bb1, 0, 1);
        __builtin_amdgcn_s_setprio(0); G256_BAR;

        // ---- ph2: stage B c0,c1(kt+2); MMA Q10(a1,bb0)
        if (st2) { GO_STAGE_B(buf, 0, kqB); GO_STAGE_B(buf, 1, kqB); }
        G256_BAR; G256_LGKM(0);
        __builtin_amdgcn_s_setprio(1); GO_MMA(a1, bb0, 4, 0);
        __builtin_amdgcn_s_setprio(0); G256_BAR;

        // ---- ph3: vmcnt; pre-read a0,bb0(kt+1); MMA Q11(a1,bb1)
        if (st1) {
            if (st2) { asm volatile("s_waitcnt vmcnt(2)" ::: "memory"); }
            else     { asm volatile("s_waitcnt vmcnt(0)" ::: "memory"); }
            __builtin_amdgcn_sched_barrier(0);
            GO_LDA4(a0, nb, 0);
            GO_LDB1(bb0, nb, 0);
        }
        G256_BAR;
        __builtin_amdgcn_s_setprio(1); GO_MMA(a1, bb1, 4, 1);
        __builtin_amdgcn_s_setprio(0); G256_BAR;
    }

    // epilogue: lane holds 4 consecutive cols (float4 stores)
    float4 bi[2];
    #pragma unroll
    for (int ni = 0; ni < 2; ni++)
        bi[ni] = *(const float4*)&bias[bn + wn * 32 + ni * 16 + quad * 4];
    #pragma unroll
    for (int mi = 0; mi < 8; mi++) {
        const int row = bm + wm * 128 + mi * 16 + l16;
        #pragma unroll
        for (int ni = 0; ni < 2; ni++) {
            const int col = bn + wn * 32 + ni * 16 + quad * 4;
            float4 fv = {acc[mi][ni][0] + bi[ni].x, acc[mi][ni][1] + bi[ni].y,
                         acc[mi][ni][2] + bi[ni].z, acc[mi][ni][3] + bi[ni].w};
            *(float4*)&C[(size_t)row * N + col] = fv;
        }
    }
}

// ---------------------------------------------------------------------------
// attn_mfma v4 (reverted — best measured 76.5 us): transposed-S flash attn,
// exp2-native softmax, MFMA ones-fragment row-sum, setprio, XOR-swizzled
// K/V LDS staging, double-buffered tiles, Ps[128][PS_LD].
// Reads Q,K from QK buffer (row stride N_QK=2048; K at col offset 1024).
// Block = (bh, 128 q-rows), 4 waves x 32 q-rows, K-tile 64.
// ---------------------------------------------------------------------------
__global__ __launch_bounds__(256) void attn_mfma(
    const u16* __restrict__ QK, const u16* __restrict__ Vtg, u16* __restrict__ ctx)
{
    __shared__ u16 Ks[2][64 * 64];   // [key][d], chunk-swizzled
    __shared__ u16 Vs[2][64 * 64];   // [d][key], chunk-swizzled
    __shared__ u16 Ps[128 * PS_LD];  // [qrow][key]

    const int bh = blockIdx.x;
    const int qt = (int)(gridDim.y - 1) - (int)blockIdx.y;   // long blocks first
    const int b = bh >> 4, h = bh & 15;
    const int tid = threadIdx.x;
    const int w = tid >> 6, lane = tid & 63;
    const int l16 = lane & 15, quad = lane >> 4;

    // staging geometry: 512 chunks of 16B per 8KB tile; thread handles f, f+256
    const int r0 = tid >> 3,        c0 = tid & 7;          // f = tid
    const int r1 = (256 + tid) >> 3, c1 = tid & 7;         // f = 256+tid
    const int sw0 = c0 ^ (r0 & 7), sw1 = c1 ^ (r1 & 7);

    // Q fragments (MFMA B-operand): lane l16 <-> q-row, k = quad*8+j
    short8 q[2][2];
    #pragma unroll
    for (int m = 0; m < 2; m++) {
        const u16* qp = QK + (size_t)(b * SEQ + qt * 128 + w * 32 + m * 16 + l16) * N_QK + h * 64;
        q[m][0] = *(const short8*)&qp[quad * 8];
        q[m][1] = *(const short8*)&qp[32 + quad * 8];
    }

    // ones fragment for MFMA row-sum (bf16 1.0 = 0x3F80)
    short8 ones8;
    #pragma unroll
    for (int i = 0; i < 8; i++) ones8[i] = (short)0x3F80;

    floatx4 O[2][4];               // O^T: rows d, col qrow=l16
    floatx4 lsum[2];               // row-sum accumulator (all regs = sum)
    #pragma unroll
    for (int m = 0; m < 2; m++) {
        lsum[m] = (floatx4){0.f, 0.f, 0.f, 0.f};
        #pragma unroll
        for (int i = 0; i < 4; i++) O[m][i] = (floatx4){0.f, 0.f, 0.f, 0.f};
    }

    const int nkt = 2 * qt + 2;
    const int qrow_w_max = qt * 128 + w * 32 + 31;

    const size_t kbase = (size_t)(b * SEQ) * N_QK + D_MODEL + h * 64;
    const size_t vbase = (size_t)bh * 64 * SEQ;

    // running prefetch pointers (advance by one K-tile per iteration)
    const u16* kpa = QK + kbase + (size_t)r0 * N_QK + c0 * 8;
    const u16* kpb = QK + kbase + (size_t)r1 * N_QK + c1 * 8;
    const u16* vpa = Vtg + vbase + (size_t)r0 * SEQ + c0 * 8;
    const u16* vpb = Vtg + vbase + (size_t)r1 * SEQ + c1 * 8;

    // prologue: tile 0 -> buf 0
    {
        float4 ka = *(const float4*)kpa;
        float4 kb = *(const float4*)kpb;
        float4 va = *(const float4*)vpa;
        float4 vb = *(const float4*)vpb;
        *(float4*)&Ks[0][r0 * 64 + sw0 * 8] = ka;
        *(float4*)&Ks[0][r1 * 64 + sw1 * 8] = kb;
        *(float4*)&Vs[0][r0 * 64 + sw0 * 8] = va;
        *(float4*)&Vs[0][r1 * 64 + sw1 * 8] = vb;
    }
    kpa += (size_t)64 * N_QK; kpb += (size_t)64 * N_QK;
    vpa += 64; vpb += 64;
    __syncthreads();

    for (int kt = 0; kt < nkt; kt++) {
        const int buf = kt & 1;
        const bool pre = (kt + 1 < nkt);
        float4 ka, kb, va, vb;
        if (pre) {
            ka = *(const float4*)kpa;
            kb = *(const float4*)kpb;
            va = *(const float4*)vpa;
            vb = *(const float4*)vpb;
            kpa += (size_t)64 * N_QK; kpb += (size_t)64 * N_QK;
            vpa += 64; vpb += 64;
        }

        if (kt * 64 <= qrow_w_max) {
            // K fragments, swizzle-decoded
            short8 kf[4][2];
            #pragma unroll
            for (int ns = 0; ns < 4; ns++) {
                const int rr = ns * 16 + l16, rs = rr & 7;
                kf[ns][0] = *(short8*)&Ks[buf][rr * 64 + (quad ^ rs) * 8];
                kf[ns][1] = *(short8*)&Ks[buf][rr * 64 + ((4 + quad) ^ rs) * 8];
            }
            const bool needMask = (kt * 64 + 63 > qt * 128 + w * 32);

            #pragma unroll
            for (int m = 0; m < 2; m++) {
                floatx4 z[4];
                __builtin_amdgcn_s_setprio(1);
                #pragma unroll
                for (int ns = 0; ns < 4; ns++) {
                    floatx4 t = (floatx4){0.f, 0.f, 0.f, 0.f};
                    t = __builtin_amdgcn_mfma_f32_16x16x32_bf16(kf[ns][0], q[m][0], t, 0, 0, 0);
                    t = __builtin_amdgcn_mfma_f32_16x16x32_bf16(kf[ns][1], q[m][1], t, 0, 0, 0);
                    z[ns] = t;
                }
                __builtin_amdgcn_s_setprio(0);
                const int qrow_g = qt * 128 + w * 32 + m * 16 + l16;
                const int prow = (w * 32 + m * 16 + l16) * PS_LD;
                #pragma unroll
                for (int ns = 0; ns < 4; ns++) {
                    u16 pk[4];
                    #pragma unroll
                    for (int r = 0; r < 4; r++) {
                        float s = z[ns][r];
                        const int key = kt * 64 + ns * 16 + quad * 4 + r;
                        if (needMask && key > qrow_g) s = -INFINITY;
                        float p = __builtin_amdgcn_exp2f(s - EXP2_OFF);
                        pk[r] = f2u(p);
                    }
                    *(short4v*)&Ps[prow + ns * 16 + quad * 4] = *(short4v*)pk;
                }
            }

            short8 vf[4][2];
            #pragma unroll
            for (int ds = 0; ds < 4; ds++) {
                const int rr = ds * 16 + l16, rs = rr & 7;
                vf[ds][0] = *(short8*)&Vs[buf][rr * 64 + (quad ^ rs) * 8];
                vf[ds][1] = *(short8*)&Vs[buf][rr * 64 + ((4 + quad) ^ rs) * 8];
            }
            __builtin_amdgcn_s_setprio(1);
            #pragma unroll
            for (int m = 0; m < 2; m++) {
                const int prow = (w * 32 + m * 16 + l16) * PS_LD;
                short8 p0 = *(short8*)&Ps[prow + quad * 8];
                short8 p1 = *(short8*)&Ps[prow + 32 + quad * 8];
                lsum[m] = __builtin_amdgcn_mfma_f32_16x16x32_bf16(ones8, p0, lsum[m], 0, 0, 0);
                lsum[m] = __builtin_amdgcn_mfma_f32_16x16x32_bf16(ones8, p1, lsum[m], 0, 0, 0);
                #pragma unroll
                for (int ds = 0; ds < 4; ds++) {
                    O[m][ds] = __builtin_amdgcn_mfma_f32_16x16x32_bf16(vf[ds][0], p0, O[m][ds], 0, 0, 0);
                    O[m][ds] = __builtin_amdgcn_mfma_f32_16x16x32_bf16(vf[ds][1], p1, O[m][ds], 0, 0, 0);
                }
            }
            __builtin_amdgcn_s_setprio(0);
        }

        if (pre) {
            const int nb = buf ^ 1;
            *(float4*)&Ks[nb][r0 * 64 + sw0 * 8] = ka;
            *(float4*)&Ks[nb][r1 * 64 + sw1 * 8] = kb;
            *(float4*)&Vs[nb][r0 * 64 + sw0 * 8] = va;
            *(float4*)&Vs[nb][r1 * 64 + sw1 * 8] = vb;
        }
        __syncthreads();
    }

    // epilogue: O^T / l -> ctx[qrow][d], packed 8 B stores
    #pragma unroll
    for (int m = 0; m < 2; m++) {
        const float inv = 1.0f / lsum[m][0];
        const size_t base = (size_t)(b * SEQ + qt * 128 + w * 32 + m * 16 + l16) * D_MODEL + h * 64;
        #pragma unroll
        for (int ds = 0; ds < 4; ds++) {
            u16 o[4];
            #pragma unroll
            for (int r = 0; r < 4; r++) o[r] = f2u(O[m][ds][r] * inv);
            *(short4v*)&ctx[base + ds * 16 + quad * 4] = *(short4v*)o;
        }
    }
}

// ---------------------------------------------------------------------------
extern "C" void kernel_launch(void* const* d_in, const int* in_sizes, int n_in,
                              void* d_out, int out_size, void* d_ws, size_t ws_size,
                              hipStream_t stream) {
    const float* x  = (const float*)d_in[0];
    const float* Wq = (const float*)d_in[1];
    const float* bq = (const float*)d_in[2];
    const float* Wk = (const float*)d_in[3];
    const float* bk = (const float*)d_in[4];
    const float* Wv = (const float*)d_in[5];
    const float* bv = (const float*)d_in[6];
    const float* Wo = (const float*)d_in[7];
    const float* bo = (const float*)d_in[8];
    float* out = (float*)d_out;

    // workspace (bytes): total 0x5840000 = 92.3 MB, no overlays (race-free:
    // gemm_qkv now writes Vtg directly, so Vtg must not alias its input xb)
    char* ws = (char*)d_ws;
    float* biasp = (float*)ws;                       // 16 KB
    u16*   Wpt   = (u16*)(ws + 0x10000);             // 6 MB  [3072][1024]
    u16*   Wot   = (u16*)(ws + 0x620000);            // 2 MB  [1024][1024]
    u16*   xb    = (u16*)(ws + 0x840000);            // 16 MB [8192][1024]
    u16*   QK    = (u16*)(ws + 0x1840000);           // 32 MB [8192][2048]
    u16*   Vtg   = (u16*)(ws + 0x3840000);           // 16 MB [64][64][2048]
    u16*   ctx   = (u16*)(ws + 0x4840000);           // 16 MB [8192][1024]

    prep<<<5121, 256, 0, stream>>>(x, Wq, Wk, Wv, Wo, bq, bk, bv, bo,
                                   xb, Wpt, Wot, biasp);

    gemm_qkv<<<dim3(N_QKV / 192, M_ROWS / 256), 512, 0, stream>>>(
        xb, Wpt, biasp, QK, Vtg, M_ROWS, N_QKV, D_MODEL);

    attn_mfma<<<dim3(BATCH * NH, SEQ / 128), 256, 0, stream>>>(QK, Vtg, ctx);

    gemm_out<<<dim3(D_MODEL / 128, M_ROWS / 256), 512, 0, stream>>>(
        ctx, Wot, biasp + N_QKV, out, M_ROWS, D_MODEL, D_MODEL);
}